// Round 15
// baseline (512.123 us; speedup 1.0000x reference)
//
#include <hip/hip_runtime.h>
#include <cstdint>
#include <cstddef>

constexpr int NB = 64;     // graphs
constexpr int NN = 1024;   // nodes/graph
constexpr int NE = 16384;  // edges/graph
constexpr int NCH = 16;    // CSR-build chunks per graph
constexpr int CHE = NE / NCH;
constexpr float C_BETA = 0.04879016417f;   // log(0.1/2 + 1)

typedef __attribute__((ext_vector_type(8))) short s8v;   // 8 bf16 (4 VGPRs)
typedef __attribute__((ext_vector_type(4))) float f4v;

__device__ inline float bf2f(ushort u){ union{uint u;float f;} v; v.u=((uint)u)<<16; return v.f; }
__device__ inline ushort f2bf(float f){ union{float f;uint u;} v; v.f=f; uint r=v.u+0x7fffu+((v.u>>16)&1u); return (ushort)(r>>16); }
__device__ inline void up8(uint4 x, float* o){
  o[0]=bf2f((ushort)x.x); o[1]=bf2f((ushort)(x.x>>16));
  o[2]=bf2f((ushort)x.y); o[3]=bf2f((ushort)(x.y>>16));
  o[4]=bf2f((ushort)x.z); o[5]=bf2f((ushort)(x.z>>16));
  o[6]=bf2f((ushort)x.w); o[7]=bf2f((ushort)(x.w>>16));
}
__device__ inline uint pk2(float a, float b){ return (uint)f2bf(a) | ((uint)f2bf(b)<<16); }
__device__ inline uint4 pk8(const float* f){
  uint4 v; v.x=pk2(f[0],f[1]); v.y=pk2(f[2],f[3]); v.z=pk2(f[4],f[5]); v.w=pk2(f[6],f[7]); return v;
}
// XCD-bijective swizzle: requires grid = NB*bpg, NB=64
__device__ inline int swz8(int bid, int bpg){
  int xcd = bid & 7, j = bid >> 3;
  return (xcd * (NB/8) + j / bpg) * bpg + (j % bpg);
}

// ---------------- CSR build: 2-pass counting sort, full-GPU width ----------------
// Block mapping b = blk&63, ch = blk>>6: all chunks of graph b share XCD b%8.

__global__ __launch_bounds__(256) void hist_k(const int* __restrict__ ei,
    const float* __restrict__ ew, int* __restrict__ phist, float* __restrict__ pdegw) {
  int blk = blockIdx.x;               // NB*NCH
  int b = blk & 63, ch = blk >> 6;
  __shared__ int hc[NN];
  __shared__ float hw[NN];
  int t = threadIdx.x;
  for (int i = t; i < NN; i += 256) { hc[i] = 0; hw[i] = 0.f; }
  __syncthreads();
  const int* dstb = ei + (size_t)b * 2 * NE + NE + ch * CHE;
  const float* ewb = ew + (size_t)b * NE + ch * CHE;
  for (int e = t; e < CHE; e += 256) {
    int d = dstb[e];
    atomicAdd(&hc[d], 1);
    atomicAdd(&hw[d], ewb[e]);
  }
  __syncthreads();
  size_t o = ((size_t)b * NCH + ch) * NN;
  for (int i = t; i < NN; i += 256) {
    phist[o + i] = hc[i];
    pdegw[o + i] = hw[i];
  }
}

__global__ __launch_bounds__(1024) void scan2_k(int* __restrict__ phist,
    const float* __restrict__ pdegw, float* __restrict__ dinvw,
    float* __restrict__ dinvu, int* __restrict__ rowptr) {
  int b = blockIdx.x, t = threadIdx.x;
  size_t base = (size_t)b * NCH * NN;
  int h[NCH];
  int cnt = 0; float dw = 1.0f;   // self-loop weight 1
#pragma unroll
  for (int c = 0; c < NCH; ++c) {
    h[c] = phist[base + c * NN + t];
    cnt += h[c];
    dw += pdegw[base + c * NN + t];
  }
  dinvw[b * NN + t] = rsqrtf(dw);
  dinvu[b * NN + t] = rsqrtf(1.0f + (float)cnt);
  __shared__ int ss[NN];
  ss[t] = cnt;
  __syncthreads();
  for (int off = 1; off < NN; off <<= 1) {
    int xv = (t >= off) ? ss[t - off] : 0;
    __syncthreads();
    ss[t] += xv;
    __syncthreads();
  }
  rowptr[b * (NN + 1) + t + 1] = ss[t];
  if (t == 0) rowptr[b * (NN + 1)] = 0;
  int excl = ss[t] - cnt;
#pragma unroll
  for (int c = 0; c < NCH; ++c) {
    phist[base + c * NN + t] = excl;
    excl += h[c];
  }
}

// scatter: single packed array {src, wn}; unweighted norm recomputed on the fly in prop.
__global__ __launch_bounds__(256) void scatter2_k(const int* __restrict__ ei,
    const float* __restrict__ ew, const int* __restrict__ coff,
    const float* __restrict__ dinvw, int2* __restrict__ peW) {
  int blk = blockIdx.x;
  int b = blk & 63, ch = blk >> 6;
  __shared__ int sbase[NN];
  __shared__ int sfill[NN];
  __shared__ float sdw[NN];
  int t = threadIdx.x;
  for (int i = t; i < NN; i += 256) {
    sbase[i] = coff[((size_t)b * NCH + ch) * NN + i];
    sfill[i] = 0;
    sdw[i] = dinvw[b * NN + i];
  }
  __syncthreads();
  const int* srcb = ei + (size_t)b * 2 * NE + ch * CHE;
  const int* dstb = ei + (size_t)b * 2 * NE + NE + ch * CHE;
  const float* ewb = ew + (size_t)b * NE + ch * CHE;
  int2* pwb = peW + (size_t)b * NE;
  for (int e = t; e < CHE; e += 256) {
    int s = srcb[e], d = dstb[e];
    int pos = sbase[d] + atomicAdd(&sfill[d], 1);
    pwb[pos] = make_int2(s, __float_as_int(sdw[s] * ewb[e] * sdw[d]));
  }
}

// ---------------- weight conversions ----------------

__device__ inline void wcv(const float* __restrict__ W, ushort* __restrict__ Wt,
                           int idx, int K, int N, int Kp) {
  int n = idx / Kp, k = idx % Kp;
  Wt[idx] = (k < K) ? f2bf(W[(size_t)k * N + n]) : (ushort)0;
}

__global__ void wconv_all_k(const float* W1, const float* W2, const float* W3,
                            const float* W4, const float* Wl, const float* Wr,
                            const float* Wg1, const float* Wm, const float* Wg2,
                            ushort* Wt1, ushort* Wt2, ushort* Wt3, ushort* Wt4,
                            ushort* WtLR, ushort* Wtg1, ushort* Wtm, ushort* Wtg2) {
  int bb = blockIdx.x, t = threadIdx.x;
  if      (bb < 320) wcv(W1, Wt1, bb * 256 + t, 300, 256, 320);
  else if (bb < 448) wcv(W2, Wt2, (bb - 320) * 256 + t, 256, 128, 256);
  else if (bb < 480) wcv(W3, Wt3, (bb - 448) * 256 + t, 128, 64, 128);
  else if (bb < 488) wcv(W4, Wt4, (bb - 480) * 256 + t, 64, 32, 64);
  else if (bb < 504) wcv(Wl, WtLR, (bb - 488) * 256 + t, 32, 128, 32);
  else if (bb < 520) wcv(Wr, WtLR + 128 * 32, (bb - 504) * 256 + t, 32, 128, 32);
  else if (bb < 584) wcv(Wg1, Wtg1, (bb - 520) * 256 + t, 128, 128, 128);
  else if (bb < 712) wcv(Wm, Wtm, (bb - 584) * 256 + t, 128, 256, 128);
  else               wcv(Wg2, Wtg2, (bb - 712) * 256 + t, 256, 256, 256);
}

// ---------------- MFMA bf16 GEMM with register-prefetch pipeline ----------------
// C[M,N] = A[M,K] @ W[K,N] (Wt = W^T bf16).  BM = WR*32, 4 waves 2x2.
// Per iteration: store regs->LDS, barrier, ISSUE next-tile loads, MFMA, barrier.
// AF32: A fp32 row-stride 300 converted during staging (K padded to 320).
// MODE 0: C = acc.  MODE 2: C = relu((1-beta)*Z + beta*acc).

template<int WR, int NI, int MODE, int AF32>
__global__ __launch_bounds__(256) void mgemm_k(const ushort* __restrict__ A,
    const float* __restrict__ Af, const ushort* __restrict__ Bt,
    const ushort* __restrict__ Z, ushort* __restrict__ C, int M, int K, int N) {
  constexpr int BM = WR * 32;
  constexpr int BN = NI * 32;
  constexpr int KR = 300;
  constexpr int NAC = (BM * 4 + 255) / 256;   // A 16B-chunks per thread
  constexpr int NBC = (BN * 4 + 255) / 256;   // B 16B-chunks per thread
  __shared__ ushort As[BM][40];
  __shared__ ushort Bs[BN][40];
  int tid = threadIdx.x;
  int wave = tid >> 6, lane = tid & 63;
  int bm = blockIdx.y * BM, bn = blockIdx.x * BN;
  int wm = (wave >> 1) * (WR * 16), wn = (wave & 1) * (NI * 16);
  f4v acc[WR][NI];
#pragma unroll
  for (int a = 0; a < WR; ++a)
#pragma unroll
    for (int b = 0; b < NI; ++b)
#pragma unroll
      for (int q = 0; q < 4; ++q) acc[a][b][q] = 0.f;

  uint4 raw[NAC];
  float fa[AF32 ? NAC : 1][8];
  uint4 rbw[NBC];

  auto loadA = [&](int k0) {
#pragma unroll
    for (int u = 0; u < NAC; ++u) {
      int c = tid + u * 256;
      if (c < BM * 4) {
        int row = c >> 2, kc = (c & 3) * 8;
        if (AF32) {
          const float* xr = Af + (size_t)(bm + row) * KR + k0 + kc;
          if (k0 + kc + 8 <= KR) {
            float4 a = *(const float4*)xr;
            float4 bq = *(const float4*)(xr + 4);
            fa[u][0]=a.x; fa[u][1]=a.y; fa[u][2]=a.z; fa[u][3]=a.w;
            fa[u][4]=bq.x; fa[u][5]=bq.y; fa[u][6]=bq.z; fa[u][7]=bq.w;
          } else {
#pragma unroll
            for (int j = 0; j < 8; ++j) fa[u][j] = (k0 + kc + j < KR) ? xr[j] : 0.f;
          }
        } else {
          raw[u] = *(const uint4*)&A[(size_t)(bm + row) * K + k0 + kc];
        }
      }
    }
  };
  auto loadB = [&](int k0) {
#pragma unroll
    for (int u = 0; u < NBC; ++u) {
      int c = tid + u * 256;
      if (c < BN * 4) {
        int col = c >> 2, kc = (c & 3) * 8;
        rbw[u] = *(const uint4*)&Bt[(size_t)(bn + col) * K + k0 + kc];
      }
    }
  };
  auto storeLDS = [&]() {
#pragma unroll
    for (int u = 0; u < NAC; ++u) {
      int c = tid + u * 256;
      if (c < BM * 4) {
        int row = c >> 2, kc = (c & 3) * 8;
        *(uint4*)&As[row][kc] = AF32 ? pk8(fa[u]) : raw[u];
      }
    }
#pragma unroll
    for (int u = 0; u < NBC; ++u) {
      int c = tid + u * 256;
      if (c < BN * 4) {
        int col = c >> 2, kc = (c & 3) * 8;
        *(uint4*)&Bs[col][kc] = rbw[u];
      }
    }
  };

  int r = lane & 15, kg = (lane >> 4) * 8;
  loadA(0); loadB(0);
  for (int k0 = 0; k0 < K; k0 += 32) {
    storeLDS();
    __syncthreads();
    if (k0 + 32 < K) { loadA(k0 + 32); loadB(k0 + 32); }   // in flight across MFMA phase
    s8v af[WR], bf[NI];
#pragma unroll
    for (int mi = 0; mi < WR; ++mi) af[mi] = *(const s8v*)&As[wm + mi * 16 + r][kg];
#pragma unroll
    for (int ni = 0; ni < NI; ++ni) bf[ni] = *(const s8v*)&Bs[wn + ni * 16 + r][kg];
#pragma unroll
    for (int mi = 0; mi < WR; ++mi)
#pragma unroll
      for (int ni = 0; ni < NI; ++ni)
        acc[mi][ni] = __builtin_amdgcn_mfma_f32_16x16x32_bf16(af[mi], bf[ni], acc[mi][ni], 0, 0, 0);
    __syncthreads();
  }
  int col = lane & 15, rowg = (lane >> 4) * 4;
#pragma unroll
  for (int mi = 0; mi < WR; ++mi)
#pragma unroll
    for (int ni = 0; ni < NI; ++ni)
#pragma unroll
      for (int q = 0; q < 4; ++q) {
        int row = bm + wm + mi * 16 + rowg + q;
        int cc = bn + wn + ni * 16 + col;
        size_t idx = (size_t)row * N + cc;
        float v = acc[mi][ni][q];
        if (MODE == 2) v = fmaxf((1.f - C_BETA) * bf2f(Z[idx]) + C_BETA * v, 0.f);
        C[idx] = f2bf(v);
      }
}

// ---------------- graph propagation (packed dst-CSR gather via L2, bf16 I/O) ----------------
// acc = dinv[i]^2*in[i,:] + sum_p w[p]*in[src[p],:]
// WSEL 0: w = pe.y.  WSEL 1: w = dinv[s]*dinv[i] (on-the-fly).
// MODE 0: out = relu(acc + bias).  MODE 1: out = 0.5*acc + 0.5*x0.

template<int D, int MODE, int WSEL>
__global__ __launch_bounds__(256) void prop_k(const ushort* __restrict__ in,
    ushort* __restrict__ out, const int2* __restrict__ pedge,
    const float* __restrict__ dinv, const int* __restrict__ rowptr,
    const float* __restrict__ bias, const ushort* __restrict__ x0) {
  constexpr int TPN = D / 8, NPB = 256 / TPN, BPG = NN / NPB;
  int t = threadIdx.x;
  int bid = swz8(blockIdx.x, BPG);
  int tn = t / TPN, cl = t % TPN;
  int node = bid * NPB + tn;
  int b = node >> 10, i = node & 1023;
  float di = dinv[node];
  float f[8], acc[8];
  uint4 ov = *(const uint4*)&in[(size_t)node * D + cl * 8];
  up8(ov, f);
  float w0 = di * di;
#pragma unroll
  for (int j = 0; j < 8; ++j) acc[j] = w0 * f[j];
  int r0 = rowptr[b * (NN + 1) + i], r1 = rowptr[b * (NN + 1) + i + 1];
  const int2* pe = pedge + (size_t)b * NE;
  const float* dvb = dinv + b * NN;
  const ushort* inb = in + (size_t)b * NN * D;
  int p = r0;
  for (; p + 4 <= r1; p += 4) {      // 4-way unroll: independent loads
    int2 e0 = pe[p], e1 = pe[p + 1], e2 = pe[p + 2], e3 = pe[p + 3];
    float wa, wb2, wc, wd;
    if (WSEL == 0) {
      wa = __int_as_float(e0.y); wb2 = __int_as_float(e1.y);
      wc = __int_as_float(e2.y); wd = __int_as_float(e3.y);
    } else {
      wa = dvb[e0.x] * di; wb2 = dvb[e1.x] * di;
      wc = dvb[e2.x] * di; wd = dvb[e3.x] * di;
    }
    uint4 rv0 = *(const uint4*)&inb[(size_t)e0.x * D + cl * 8];
    uint4 rv1 = *(const uint4*)&inb[(size_t)e1.x * D + cl * 8];
    uint4 rv2 = *(const uint4*)&inb[(size_t)e2.x * D + cl * 8];
    uint4 rv3 = *(const uint4*)&inb[(size_t)e3.x * D + cl * 8];
    up8(rv0, f);
#pragma unroll
    for (int j = 0; j < 8; ++j) acc[j] += wa * f[j];
    up8(rv1, f);
#pragma unroll
    for (int j = 0; j < 8; ++j) acc[j] += wb2 * f[j];
    up8(rv2, f);
#pragma unroll
    for (int j = 0; j < 8; ++j) acc[j] += wc * f[j];
    up8(rv3, f);
#pragma unroll
    for (int j = 0; j < 8; ++j) acc[j] += wd * f[j];
  }
  for (; p < r1; ++p) {
    int2 e = pe[p];
    float w = (WSEL == 0) ? __int_as_float(e.y) : dvb[e.x] * di;
    uint4 rv = *(const uint4*)&inb[(size_t)e.x * D + cl * 8];
    up8(rv, f);
#pragma unroll
    for (int j = 0; j < 8; ++j) acc[j] += w * f[j];
  }
  size_t ob = (size_t)node * D + cl * 8;
  if (MODE == 0) {
#pragma unroll
    for (int j = 0; j < 8; ++j) acc[j] = fmaxf(acc[j] + bias[cl * 8 + j], 0.f);
  } else {
    uint4 xv = *(const uint4*)&x0[ob];
    up8(xv, f);
#pragma unroll
    for (int j = 0; j < 8; ++j) acc[j] = 0.5f * acc[j] + 0.5f * f[j];
  }
  *(uint4*)&out[ob] = pk8(acc);
}

// ---------------- GATv2: fused flash-style with defer-max ----------------
// xlr layout: [node][256]: ch 0-127 = xl, 128-255 = xr.

#define GAT_UPD(P, FL)                                            \
  if (P > m + 8.f) {               /* rare: rescale */            \
    float sc = __expf(m - P);                                     \
    den *= sc;                                                    \
    _Pragma("unroll")                                             \
    for (int j = 0; j < 8; ++j) acc[j] *= sc;                     \
    m = P;                                                        \
    den += 1.f;                                                   \
    _Pragma("unroll")                                             \
    for (int j = 0; j < 8; ++j) acc[j] += FL[j];                  \
  } else {                                                        \
    float ex = __expf(P - m);                                     \
    den += ex;                                                    \
    _Pragma("unroll")                                             \
    for (int j = 0; j < 8; ++j) acc[j] += ex * FL[j];             \
  }

__global__ __launch_bounds__(256) void gat_fused_k(const ushort* __restrict__ xlr,
    const int2* __restrict__ pedge, const int* __restrict__ rowptr,
    const float* __restrict__ att, const float* __restrict__ bg,
    ushort* __restrict__ out) {
  int bid = swz8(blockIdx.x, NN / 16);   // 16 nodes/block
  int t = threadIdx.x;
  int tn = t >> 4, cl = t & 15;
  int node = bid * 16 + tn;
  int b = node >> 10, i = node & 1023;
  int ch = cl * 8;
  int r0 = rowptr[b * (NN + 1) + i], r1 = rowptr[b * (NN + 1) + i + 1];
  const ushort* xb = xlr + (size_t)b * NN * 256;
  const int2* pe = pedge + (size_t)b * NE;
  float fr[8], at[8];
  {
    uint4 rv = *(const uint4*)&xb[(size_t)i * 256 + 128 + ch];  // xr[i] chunk
    up8(rv, fr);
#pragma unroll
    for (int j = 0; j < 8; ++j) at[j] = att[ch + j];
  }
  float m, den, acc[8];
  {
    float fs[8];
    uint4 sv = *(const uint4*)&xb[(size_t)i * 256 + ch];        // xl[i] (self)
    up8(sv, fs);
    float part = 0.f;
#pragma unroll
    for (int j = 0; j < 8; ++j) {
      float v = fs[j] + fr[j];
      part += fmaxf(v, 0.2f * v) * at[j];
    }
    part += __shfl_xor(part, 1);
    part += __shfl_xor(part, 2);
    m = part; den = 1.f;
#pragma unroll
    for (int j = 0; j < 8; ++j) acc[j] = fs[j];
  }
  float fl0[8], fl1[8];
  int p = r0;
  for (; p + 2 <= r1; p += 2) {
    int s0 = pe[p].x, s1 = pe[p + 1].x;
    uint4 v0 = *(const uint4*)&xb[(size_t)s0 * 256 + ch];
    uint4 v1 = *(const uint4*)&xb[(size_t)s1 * 256 + ch];
    up8(v0, fl0); up8(v1, fl1);
    float p0 = 0.f, p1 = 0.f;
#pragma unroll
    for (int j = 0; j < 8; ++j) {
      float a0 = fl0[j] + fr[j];
      float a1 = fl1[j] + fr[j];
      p0 += fmaxf(a0, 0.2f * a0) * at[j];
      p1 += fmaxf(a1, 0.2f * a1) * at[j];
    }
    p0 += __shfl_xor(p0, 1); p0 += __shfl_xor(p0, 2);
    p1 += __shfl_xor(p1, 1); p1 += __shfl_xor(p1, 2);
    GAT_UPD(p0, fl0)
    GAT_UPD(p1, fl1)
  }
  if (p < r1) {
    int s = pe[p].x;
    uint4 v0 = *(const uint4*)&xb[(size_t)s * 256 + ch];
    up8(v0, fl0);
    float p0 = 0.f;
#pragma unroll
    for (int j = 0; j < 8; ++j) {
      float a0 = fl0[j] + fr[j];
      p0 += fmaxf(a0, 0.2f * a0) * at[j];
    }
    p0 += __shfl_xor(p0, 1); p0 += __shfl_xor(p0, 2);
    GAT_UPD(p0, fl0)
  }
  float inv = 1.f / den;
#pragma unroll
  for (int j = 0; j < 8; ++j) acc[j] = fmaxf(acc[j] * inv + bg[ch + j], 0.f);
  *(uint4*)&out[(size_t)node * 128 + ch] = pk8(acc);
}

// ---------------- pooled = column-sum(h7); out = pooled @ Wo + bo ----------------

__global__ __launch_bounds__(256) void pool_part_k(const ushort* __restrict__ h7,
                                                   float* __restrict__ part) {
  int bid = blockIdx.x;                 // NB*8 blocks
  int bgr = bid >> 3, seg = bid & 7;    // 128 rows/segment
  int t = threadIdx.x;
  int rg = t >> 5, cl = t & 31;
  const ushort* hb = h7 + (size_t)bgr * NN * 256;
  float a[8] = {};
  float f[8];
  for (int r = seg * 128 + rg; r < seg * 128 + 128; r += 8) {
    uint4 v = *(const uint4*)&hb[(size_t)r * 256 + cl * 8];
    up8(v, f);
#pragma unroll
    for (int j = 0; j < 8; ++j) a[j] += f[j];
  }
  __shared__ float red[8][256];
#pragma unroll
  for (int j = 0; j < 8; ++j) red[rg][cl * 8 + j] = a[j];
  __syncthreads();
  float s = 0.f;
#pragma unroll
  for (int g = 0; g < 8; ++g) s += red[g][t];
  part[(size_t)bid * 256 + t] = s;
}

__global__ __launch_bounds__(256) void pool_out_k(const float* __restrict__ part,
    const float* __restrict__ Wo, const float* __restrict__ bo, float* __restrict__ out) {
  int bgr = blockIdx.x, t = threadIdx.x;
  float s = 0.f;
#pragma unroll
  for (int g = 0; g < 8; ++g) s += part[(size_t)(bgr * 8 + g) * 256 + t];
  __shared__ float pv[256];
  pv[t] = s;
  __syncthreads();
  if (t < 8) {
    float o = bo[t];
    for (int c = 0; c < 256; ++c) o += pv[c] * Wo[c * 8 + t];
    out[bgr * 8 + t] = o;
  }
}

__global__ void zero_out_k(float* out, int n) {
  int g = blockIdx.x * 256 + threadIdx.x;
  if (g < n) out[g] = 0.f;
}

// ---------------- launch ----------------

extern "C" void kernel_launch(void* const* d_in, const int* in_sizes, int n_in,
                              void* d_out, int out_size, void* d_ws, size_t ws_size,
                              hipStream_t stream) {
  const float* x   = (const float*)d_in[0];
  const int*   ei  = (const int*)d_in[1];
  const float* ew  = (const float*)d_in[2];
  const float* W1  = (const float*)d_in[3];
  const float* b1  = (const float*)d_in[4];
  const float* W2  = (const float*)d_in[5];
  const float* b2  = (const float*)d_in[6];
  const float* W3  = (const float*)d_in[7];
  const float* b3  = (const float*)d_in[8];
  const float* W4  = (const float*)d_in[9];
  const float* b4  = (const float*)d_in[10];
  const float* Wl  = (const float*)d_in[11];
  const float* Wr  = (const float*)d_in[12];
  const float* att = (const float*)d_in[13];
  const float* bg  = (const float*)d_in[14];
  const float* Wg1 = (const float*)d_in[15];
  const float* Wm  = (const float*)d_in[16];
  const float* bm  = (const float*)d_in[17];
  const float* Wg2 = (const float*)d_in[18];
  const float* Wo  = (const float*)d_in[23];
  const float* bo  = (const float*)d_in[24];
  float* out = (float*)d_out;

  const int M = NB * NN;

  char* wp = (char*)d_ws;
  size_t used = 0;
  auto alloc = [&](size_t bytes) -> void* {
    void* p = (void*)wp;
    size_t a = (bytes + 255) & ~(size_t)255;
    wp += a; used += a;
    return p;
  };
  float* dinvw = (float*)alloc((size_t)NB * NN * 4);
  float* dinvu = (float*)alloc((size_t)NB * NN * 4);
  int*   rowptr= (int*)alloc((size_t)NB * (NN + 1) * 4);
  int*   phist = (int*)alloc((size_t)NB * NCH * NN * 4);
  float* pdegw = (float*)alloc((size_t)NB * NCH * NN * 4);
  int2*  peW   = (int2*)alloc((size_t)NB * NE * 8);
  float* part  = (float*)alloc((size_t)NB * 8 * 256 * 4);
  ushort* Wt1  = (ushort*)alloc((size_t)256 * 320 * 2);
  ushort* Wt2  = (ushort*)alloc((size_t)128 * 256 * 2);
  ushort* Wt3  = (ushort*)alloc((size_t)64 * 128 * 2);
  ushort* Wt4  = (ushort*)alloc((size_t)32 * 64 * 2);
  ushort* WtLR = (ushort*)alloc((size_t)256 * 32 * 2);
  ushort* Wtg1 = (ushort*)alloc((size_t)128 * 128 * 2);
  ushort* Wtm  = (ushort*)alloc((size_t)256 * 128 * 2);
  ushort* Wtg2 = (ushort*)alloc((size_t)256 * 256 * 2);
  ushort* B1 = (ushort*)alloc((size_t)M * 256 * 2);   // h1
  ushort* B2 = (ushort*)alloc((size_t)M * 256 * 2);
  ushort* B3 = (ushort*)alloc((size_t)M * 256 * 2);
  ushort* B4 = (ushort*)alloc((size_t)M * 256 * 2);   // xlr
  ushort* B2a = B2, *B2b = B2 + (size_t)M * 128;
  ushort* B3a = B3, *B3b = B3 + (size_t)M * 128;

  if (used > ws_size) {
    zero_out_k<<<(out_size + 255) / 256, 256, 0, stream>>>(out, out_size);
    return;
  }

  // ---- weight conversions ----
  wconv_all_k<<<968, 256, 0, stream>>>(W1, W2, W3, W4, Wl, Wr, Wg1, Wm, Wg2,
                                       Wt1, Wt2, Wt3, Wt4, WtLR, Wtg1, Wtm, Wtg2);

  // ---- CSR build (2-pass counting sort, XCD-affine chunks) ----
  hist_k<<<NB * NCH, 256, 0, stream>>>(ei, ew, phist, pdegw);
  scan2_k<<<NB, 1024, 0, stream>>>(phist, pdegw, dinvw, dinvu, rowptr);
  scatter2_k<<<NB * NCH, 256, 0, stream>>>(ei, ew, phist, dinvw, peW);

  // ---- GCN stack (BM=64 tiles; GEMM1 reads fp32 x directly) ----
  mgemm_k<2,4,0,1><<<dim3(2, M / 64), 256, 0, stream>>>(nullptr, x, Wt1, nullptr, B2, M, 320, 256);
  prop_k<256,0,0><<<M / 8, 256, 0, stream>>>(B2, B1, peW, dinvw, rowptr, b1, nullptr);    // h1
  mgemm_k<2,4,0,0><<<dim3(1, M / 64), 256, 0, stream>>>(B1, nullptr, Wt2, nullptr, B2a, M, 256, 128);
  prop_k<128,0,0><<<M / 16, 256, 0, stream>>>(B2a, B3a, peW, dinvw, rowptr, b2, nullptr); // h2
  mgemm_k<2,2,0,0><<<dim3(1, M / 64), 256, 0, stream>>>(B3a, nullptr, Wt3, nullptr, B2a, M, 128, 64);
  prop_k<64,0,0><<<M / 32, 256, 0, stream>>>(B2a, B3b, peW, dinvw, rowptr, b3, nullptr);  // h3
  mgemm_k<2,1,0,0><<<dim3(1, M / 64), 256, 0, stream>>>(B3b, nullptr, Wt4, nullptr, B2a, M, 64, 32);
  prop_k<32,0,0><<<M / 64, 256, 0, stream>>>(B2a, B2b, peW, dinvw, rowptr, b4, nullptr);  // h4

  // ---- GATv2 (xl|xr one GEMM; fused flash-style attention) ----
  mgemm_k<2,4,0,0><<<dim3(2, M / 64), 256, 0, stream>>>(B2b, nullptr, WtLR, nullptr, B4, M, 32, 256);
  gat_fused_k<<<M / 16, 256, 0, stream>>>(B4, peW, rowptr, att, bg, B2a);                 // hg

  // ---- GCN2Conv #1 (x0 = h2 = B3a) ----
  prop_k<128,1,0><<<M / 16, 256, 0, stream>>>(B2a, B2b, peW, dinvw, rowptr, nullptr, B3a); // z1
  mgemm_k<2,4,2,0><<<dim3(1, M / 64), 256, 0, stream>>>(B2b, nullptr, Wtg1, B2b, B2a, M, 128, 128);

  // ---- GCNConv mid (unweighted norm, on-the-fly du[s]*du[d]) ----
  mgemm_k<2,4,0,0><<<dim3(2, M / 64), 256, 0, stream>>>(B2a, nullptr, Wtm, nullptr, B3, M, 128, 256);
  prop_k<256,0,1><<<M / 8, 256, 0, stream>>>(B3, B2, peW, dinvu, rowptr, bm, nullptr);    // h6

  // ---- GCN2Conv #2 (x0 = h1 = B1) ----
  prop_k<256,1,0><<<M / 8, 256, 0, stream>>>(B2, B3, peW, dinvw, rowptr, nullptr, B1);    // z2
  mgemm_k<2,4,2,0><<<dim3(2, M / 64), 256, 0, stream>>>(B3, nullptr, Wtg2, B3, B2, M, 256, 256);

  // ---- collapsed diff-pool + output projection ----
  pool_part_k<<<NB * 8, 256, 0, stream>>>(B2, part);
  pool_out_k<<<NB, 256, 0, stream>>>(part, Wo, bo, out);
}

// Round 16
// 414.687 us; speedup vs baseline: 1.2350x; 1.2350x over previous
//
#include <hip/hip_runtime.h>
#include <cstdint>
#include <cstddef>

constexpr int NB = 64;     // graphs
constexpr int NN = 1024;   // nodes/graph
constexpr int NE = 16384;  // edges/graph
constexpr int NCH = 16;    // CSR-build chunks per graph
constexpr int CHE = NE / NCH;
constexpr float C_BETA = 0.04879016417f;   // log(0.1/2 + 1)

typedef __attribute__((ext_vector_type(8))) short s8v;   // 8 bf16 (4 VGPRs)
typedef __attribute__((ext_vector_type(4))) float f4v;

__device__ inline float bf2f(ushort u){ union{uint u;float f;} v; v.u=((uint)u)<<16; return v.f; }
__device__ inline ushort f2bf(float f){ union{float f;uint u;} v; v.f=f; uint r=v.u+0x7fffu+((v.u>>16)&1u); return (ushort)(r>>16); }
__device__ inline void up8(uint4 x, float* o){
  o[0]=bf2f((ushort)x.x); o[1]=bf2f((ushort)(x.x>>16));
  o[2]=bf2f((ushort)x.y); o[3]=bf2f((ushort)(x.y>>16));
  o[4]=bf2f((ushort)x.z); o[5]=bf2f((ushort)(x.z>>16));
  o[6]=bf2f((ushort)x.w); o[7]=bf2f((ushort)(x.w>>16));
}
__device__ inline uint pk2(float a, float b){ return (uint)f2bf(a) | ((uint)f2bf(b)<<16); }
__device__ inline uint4 pk8(const float* f){
  uint4 v; v.x=pk2(f[0],f[1]); v.y=pk2(f[2],f[3]); v.z=pk2(f[4],f[5]); v.w=pk2(f[6],f[7]); return v;
}
// XCD-bijective swizzle: requires grid = NB*bpg, NB=64
__device__ inline int swz8(int bid, int bpg){
  int xcd = bid & 7, j = bid >> 3;
  return (xcd * (NB/8) + j / bpg) * bpg + (j % bpg);
}

// ---------------- CSR build: 2-pass counting sort, full-GPU width ----------------
// Block mapping b = blk&63, ch = blk>>6: all chunks of graph b share XCD b%8.

__global__ __launch_bounds__(256) void hist_k(const int* __restrict__ ei,
    const float* __restrict__ ew, int* __restrict__ phist, float* __restrict__ pdegw) {
  int blk = blockIdx.x;               // NB*NCH
  int b = blk & 63, ch = blk >> 6;
  __shared__ int hc[NN];
  __shared__ float hw[NN];
  int t = threadIdx.x;
  for (int i = t; i < NN; i += 256) { hc[i] = 0; hw[i] = 0.f; }
  __syncthreads();
  const int* dstb = ei + (size_t)b * 2 * NE + NE + ch * CHE;
  const float* ewb = ew + (size_t)b * NE + ch * CHE;
  for (int e = t; e < CHE; e += 256) {
    int d = dstb[e];
    atomicAdd(&hc[d], 1);
    atomicAdd(&hw[d], ewb[e]);
  }
  __syncthreads();
  size_t o = ((size_t)b * NCH + ch) * NN;
  for (int i = t; i < NN; i += 256) {
    phist[o + i] = hc[i];
    pdegw[o + i] = hw[i];
  }
}

__global__ __launch_bounds__(1024) void scan2_k(int* __restrict__ phist,
    const float* __restrict__ pdegw, float* __restrict__ dinvw,
    float* __restrict__ dinvu, int* __restrict__ rowptr) {
  int b = blockIdx.x, t = threadIdx.x;
  size_t base = (size_t)b * NCH * NN;
  int h[NCH];
  int cnt = 0; float dw = 1.0f;   // self-loop weight 1
#pragma unroll
  for (int c = 0; c < NCH; ++c) {
    h[c] = phist[base + c * NN + t];
    cnt += h[c];
    dw += pdegw[base + c * NN + t];
  }
  dinvw[b * NN + t] = rsqrtf(dw);
  dinvu[b * NN + t] = rsqrtf(1.0f + (float)cnt);
  __shared__ int ss[NN];
  ss[t] = cnt;
  __syncthreads();
  for (int off = 1; off < NN; off <<= 1) {
    int xv = (t >= off) ? ss[t - off] : 0;
    __syncthreads();
    ss[t] += xv;
    __syncthreads();
  }
  rowptr[b * (NN + 1) + t + 1] = ss[t];
  if (t == 0) rowptr[b * (NN + 1)] = 0;
  int excl = ss[t] - cnt;
#pragma unroll
  for (int c = 0; c < NCH; ++c) {
    phist[base + c * NN + t] = excl;
    excl += h[c];
  }
}

// scatter: single packed array {src, wn}; unweighted norm recomputed on the fly in prop.
__global__ __launch_bounds__(256) void scatter2_k(const int* __restrict__ ei,
    const float* __restrict__ ew, const int* __restrict__ coff,
    const float* __restrict__ dinvw, int2* __restrict__ peW) {
  int blk = blockIdx.x;
  int b = blk & 63, ch = blk >> 6;
  __shared__ int sbase[NN];
  __shared__ int sfill[NN];
  __shared__ float sdw[NN];
  int t = threadIdx.x;
  for (int i = t; i < NN; i += 256) {
    sbase[i] = coff[((size_t)b * NCH + ch) * NN + i];
    sfill[i] = 0;
    sdw[i] = dinvw[b * NN + i];
  }
  __syncthreads();
  const int* srcb = ei + (size_t)b * 2 * NE + ch * CHE;
  const int* dstb = ei + (size_t)b * 2 * NE + NE + ch * CHE;
  const float* ewb = ew + (size_t)b * NE + ch * CHE;
  int2* pwb = peW + (size_t)b * NE;
  for (int e = t; e < CHE; e += 256) {
    int s = srcb[e], d = dstb[e];
    int pos = sbase[d] + atomicAdd(&sfill[d], 1);
    pwb[pos] = make_int2(s, __float_as_int(sdw[s] * ewb[e] * sdw[d]));
  }
}

// ---------------- weight conversions ----------------

__device__ inline void wcv(const float* __restrict__ W, ushort* __restrict__ Wt,
                           int idx, int K, int N, int Kp) {
  int n = idx / Kp, k = idx % Kp;
  Wt[idx] = (k < K) ? f2bf(W[(size_t)k * N + n]) : (ushort)0;
}

__global__ void wconv_all_k(const float* W1, const float* W2, const float* W3,
                            const float* W4, const float* Wl, const float* Wr,
                            const float* Wg1, const float* Wm, const float* Wg2,
                            ushort* Wt1, ushort* Wt2, ushort* Wt3, ushort* Wt4,
                            ushort* WtLR, ushort* Wtg1, ushort* Wtm, ushort* Wtg2) {
  int bb = blockIdx.x, t = threadIdx.x;
  if      (bb < 320) wcv(W1, Wt1, bb * 256 + t, 300, 256, 320);
  else if (bb < 448) wcv(W2, Wt2, (bb - 320) * 256 + t, 256, 128, 256);
  else if (bb < 480) wcv(W3, Wt3, (bb - 448) * 256 + t, 128, 64, 128);
  else if (bb < 488) wcv(W4, Wt4, (bb - 480) * 256 + t, 64, 32, 64);
  else if (bb < 504) wcv(Wl, WtLR, (bb - 488) * 256 + t, 32, 128, 32);
  else if (bb < 520) wcv(Wr, WtLR + 128 * 32, (bb - 504) * 256 + t, 32, 128, 32);
  else if (bb < 584) wcv(Wg1, Wtg1, (bb - 520) * 256 + t, 128, 128, 128);
  else if (bb < 712) wcv(Wm, Wtm, (bb - 584) * 256 + t, 128, 256, 128);
  else               wcv(Wg2, Wtg2, (bb - 712) * 256 + t, 256, 256, 256);
}

// ---------------- MFMA bf16 GEMM: C[M,N] = A[M,K] @ W[K,N]  (Wt = W^T bf16) ----------------
// BM = WR*32 (4 waves, 2x2 wave grid).  AF32: A fp32 row-stride 300, converted in staging.
// MODE 0: C = acc.  MODE 2: C = relu((1-beta)*Z + beta*acc).

template<int WR, int NI, int MODE, int AF32>
__global__ __launch_bounds__(256) void mgemm_k(const ushort* __restrict__ A,
    const float* __restrict__ Af, const ushort* __restrict__ Bt,
    const ushort* __restrict__ Z, ushort* __restrict__ C, int M, int K, int N) {
  constexpr int BM = WR * 32;
  constexpr int BN = NI * 32;
  constexpr int KR = 300;          // real K for AF32 path
  __shared__ ushort As[BM][40];
  __shared__ ushort Bs[BN][40];
  int tid = threadIdx.x;
  int wave = tid >> 6, lane = tid & 63;
  int bm = blockIdx.y * BM, bn = blockIdx.x * BN;
  int wm = (wave >> 1) * (WR * 16), wn = (wave & 1) * (NI * 16);
  f4v acc[WR][NI];
#pragma unroll
  for (int a = 0; a < WR; ++a)
#pragma unroll
    for (int b = 0; b < NI; ++b)
#pragma unroll
      for (int q = 0; q < 4; ++q) acc[a][b][q] = 0.f;
  int r = lane & 15, kg = (lane >> 4) * 8;
  for (int k0 = 0; k0 < K; k0 += 32) {
#pragma unroll
    for (int c = tid; c < BM * 4; c += 256) {
      int row = c >> 2, kc = (c & 3) * 8;
      if (AF32) {
        const float* xr = Af + (size_t)(bm + row) * KR + k0 + kc;
        float f[8];
        if (k0 + kc + 8 <= KR) {
          float4 a = *(const float4*)xr;
          float4 bq = *(const float4*)(xr + 4);
          f[0]=a.x; f[1]=a.y; f[2]=a.z; f[3]=a.w;
          f[4]=bq.x; f[5]=bq.y; f[6]=bq.z; f[7]=bq.w;
        } else {
#pragma unroll
          for (int j = 0; j < 8; ++j) f[j] = (k0 + kc + j < KR) ? xr[j] : 0.f;
        }
        *(uint4*)&As[row][kc] = pk8(f);
      } else {
        *(uint4*)&As[row][kc] = *(const uint4*)&A[(size_t)(bm + row) * K + k0 + kc];
      }
    }
#pragma unroll
    for (int c = tid; c < BN * 4; c += 256) {
      int col = c >> 2, kc = (c & 3) * 8;
      *(uint4*)&Bs[col][kc] = *(const uint4*)&Bt[(size_t)(bn + col) * K + k0 + kc];
    }
    __syncthreads();
    s8v af[WR], bf[NI];
#pragma unroll
    for (int mi = 0; mi < WR; ++mi) af[mi] = *(const s8v*)&As[wm + mi * 16 + r][kg];
#pragma unroll
    for (int ni = 0; ni < NI; ++ni) bf[ni] = *(const s8v*)&Bs[wn + ni * 16 + r][kg];
#pragma unroll
    for (int mi = 0; mi < WR; ++mi)
#pragma unroll
      for (int ni = 0; ni < NI; ++ni)
        acc[mi][ni] = __builtin_amdgcn_mfma_f32_16x16x32_bf16(af[mi], bf[ni], acc[mi][ni], 0, 0, 0);
    __syncthreads();
  }
  int col = lane & 15, rowg = (lane >> 4) * 4;
#pragma unroll
  for (int mi = 0; mi < WR; ++mi)
#pragma unroll
    for (int ni = 0; ni < NI; ++ni)
#pragma unroll
      for (int q = 0; q < 4; ++q) {
        int row = bm + wm + mi * 16 + rowg + q;
        int cc = bn + wn + ni * 16 + col;
        size_t idx = (size_t)row * N + cc;
        float v = acc[mi][ni][q];
        if (MODE == 2) v = fmaxf((1.f - C_BETA) * bf2f(Z[idx]) + C_BETA * v, 0.f);
        C[idx] = f2bf(v);
      }
}

// ---------------- graph propagation (packed dst-CSR gather via L2, bf16 I/O) ----------------
// acc = dinv[i]^2*in[i,:] + sum_p w[p]*in[src[p],:]
// WSEL 0: w = pe.y.  WSEL 1: w = dinv[s]*dinv[i] (on-the-fly).
// MODE 0: out = relu(acc + bias).  MODE 1: out = 0.5*acc + 0.5*x0.

template<int D, int MODE, int WSEL>
__global__ __launch_bounds__(256) void prop_k(const ushort* __restrict__ in,
    ushort* __restrict__ out, const int2* __restrict__ pedge,
    const float* __restrict__ dinv, const int* __restrict__ rowptr,
    const float* __restrict__ bias, const ushort* __restrict__ x0) {
  constexpr int TPN = D / 8, NPB = 256 / TPN, BPG = NN / NPB;
  int t = threadIdx.x;
  int bid = swz8(blockIdx.x, BPG);
  int tn = t / TPN, cl = t % TPN;
  int node = bid * NPB + tn;
  int b = node >> 10, i = node & 1023;
  float di = dinv[node];
  float f[8], acc[8];
  uint4 ov = *(const uint4*)&in[(size_t)node * D + cl * 8];
  up8(ov, f);
  float w0 = di * di;
#pragma unroll
  for (int j = 0; j < 8; ++j) acc[j] = w0 * f[j];
  int r0 = rowptr[b * (NN + 1) + i], r1 = rowptr[b * (NN + 1) + i + 1];
  const int2* pe = pedge + (size_t)b * NE;
  const float* dvb = dinv + b * NN;
  const ushort* inb = in + (size_t)b * NN * D;
  int p = r0;
  for (; p + 4 <= r1; p += 4) {      // 4-way unroll: independent loads
    int2 e0 = pe[p], e1 = pe[p + 1], e2 = pe[p + 2], e3 = pe[p + 3];
    float wa, wb2, wc, wd;
    if (WSEL == 0) {
      wa = __int_as_float(e0.y); wb2 = __int_as_float(e1.y);
      wc = __int_as_float(e2.y); wd = __int_as_float(e3.y);
    } else {
      wa = dvb[e0.x] * di; wb2 = dvb[e1.x] * di;
      wc = dvb[e2.x] * di; wd = dvb[e3.x] * di;
    }
    uint4 rv0 = *(const uint4*)&inb[(size_t)e0.x * D + cl * 8];
    uint4 rv1 = *(const uint4*)&inb[(size_t)e1.x * D + cl * 8];
    uint4 rv2 = *(const uint4*)&inb[(size_t)e2.x * D + cl * 8];
    uint4 rv3 = *(const uint4*)&inb[(size_t)e3.x * D + cl * 8];
    up8(rv0, f);
#pragma unroll
    for (int j = 0; j < 8; ++j) acc[j] += wa * f[j];
    up8(rv1, f);
#pragma unroll
    for (int j = 0; j < 8; ++j) acc[j] += wb2 * f[j];
    up8(rv2, f);
#pragma unroll
    for (int j = 0; j < 8; ++j) acc[j] += wc * f[j];
    up8(rv3, f);
#pragma unroll
    for (int j = 0; j < 8; ++j) acc[j] += wd * f[j];
  }
  for (; p < r1; ++p) {
    int2 e = pe[p];
    float w = (WSEL == 0) ? __int_as_float(e.y) : dvb[e.x] * di;
    uint4 rv = *(const uint4*)&inb[(size_t)e.x * D + cl * 8];
    up8(rv, f);
#pragma unroll
    for (int j = 0; j < 8; ++j) acc[j] += w * f[j];
  }
  size_t ob = (size_t)node * D + cl * 8;
  if (MODE == 0) {
#pragma unroll
    for (int j = 0; j < 8; ++j) acc[j] = fmaxf(acc[j] + bias[cl * 8 + j], 0.f);
  } else {
    uint4 xv = *(const uint4*)&x0[ob];
    up8(xv, f);
#pragma unroll
    for (int j = 0; j < 8; ++j) acc[j] = 0.5f * acc[j] + 0.5f * f[j];
  }
  *(uint4*)&out[ob] = pk8(acc);
}

// ---------------- GATv2: fused flash-style with defer-max ----------------
// xlr layout: [node][256]: ch 0-127 = xl, 128-255 = xr.

#define GAT_UPD(P, FL)                                            \
  if (P > m + 8.f) {               /* rare: rescale */            \
    float sc = __expf(m - P);                                     \
    den *= sc;                                                    \
    _Pragma("unroll")                                             \
    for (int j = 0; j < 8; ++j) acc[j] *= sc;                     \
    m = P;                                                        \
    den += 1.f;                                                   \
    _Pragma("unroll")                                             \
    for (int j = 0; j < 8; ++j) acc[j] += FL[j];                  \
  } else {                                                        \
    float ex = __expf(P - m);                                     \
    den += ex;                                                    \
    _Pragma("unroll")                                             \
    for (int j = 0; j < 8; ++j) acc[j] += ex * FL[j];             \
  }

__global__ __launch_bounds__(256) void gat_fused_k(const ushort* __restrict__ xlr,
    const int2* __restrict__ pedge, const int* __restrict__ rowptr,
    const float* __restrict__ att, const float* __restrict__ bg,
    ushort* __restrict__ out) {
  int bid = swz8(blockIdx.x, NN / 16);   // 16 nodes/block
  int t = threadIdx.x;
  int tn = t >> 4, cl = t & 15;
  int node = bid * 16 + tn;
  int b = node >> 10, i = node & 1023;
  int ch = cl * 8;
  int r0 = rowptr[b * (NN + 1) + i], r1 = rowptr[b * (NN + 1) + i + 1];
  const ushort* xb = xlr + (size_t)b * NN * 256;
  const int2* pe = pedge + (size_t)b * NE;
  float fr[8], at[8];
  {
    uint4 rv = *(const uint4*)&xb[(size_t)i * 256 + 128 + ch];  // xr[i] chunk
    up8(rv, fr);
#pragma unroll
    for (int j = 0; j < 8; ++j) at[j] = att[ch + j];
  }
  float m, den, acc[8];
  {
    float fs[8];
    uint4 sv = *(const uint4*)&xb[(size_t)i * 256 + ch];        // xl[i] (self)
    up8(sv, fs);
    float part = 0.f;
#pragma unroll
    for (int j = 0; j < 8; ++j) {
      float v = fs[j] + fr[j];
      part += fmaxf(v, 0.2f * v) * at[j];
    }
    part += __shfl_xor(part, 1);
    part += __shfl_xor(part, 2);
    m = part; den = 1.f;
#pragma unroll
    for (int j = 0; j < 8; ++j) acc[j] = fs[j];
  }
  float fl0[8], fl1[8];
  int p = r0;
  for (; p + 2 <= r1; p += 2) {
    int s0 = pe[p].x, s1 = pe[p + 1].x;
    uint4 v0 = *(const uint4*)&xb[(size_t)s0 * 256 + ch];
    uint4 v1 = *(const uint4*)&xb[(size_t)s1 * 256 + ch];
    up8(v0, fl0); up8(v1, fl1);
    float p0 = 0.f, p1 = 0.f;
#pragma unroll
    for (int j = 0; j < 8; ++j) {
      float a0 = fl0[j] + fr[j];
      float a1 = fl1[j] + fr[j];
      p0 += fmaxf(a0, 0.2f * a0) * at[j];
      p1 += fmaxf(a1, 0.2f * a1) * at[j];
    }
    p0 += __shfl_xor(p0, 1); p0 += __shfl_xor(p0, 2);
    p1 += __shfl_xor(p1, 1); p1 += __shfl_xor(p1, 2);
    GAT_UPD(p0, fl0)
    GAT_UPD(p1, fl1)
  }
  if (p < r1) {
    int s = pe[p].x;
    uint4 v0 = *(const uint4*)&xb[(size_t)s * 256 + ch];
    up8(v0, fl0);
    float p0 = 0.f;
#pragma unroll
    for (int j = 0; j < 8; ++j) {
      float a0 = fl0[j] + fr[j];
      p0 += fmaxf(a0, 0.2f * a0) * at[j];
    }
    p0 += __shfl_xor(p0, 1); p0 += __shfl_xor(p0, 2);
    GAT_UPD(p0, fl0)
  }
  float inv = 1.f / den;
#pragma unroll
  for (int j = 0; j < 8; ++j) acc[j] = fmaxf(acc[j] * inv + bg[ch + j], 0.f);
  *(uint4*)&out[(size_t)node * 128 + ch] = pk8(acc);
}

// ---------------- pooled = column-sum(h7); out = pooled @ Wo + bo ----------------

__global__ __launch_bounds__(256) void pool_part_k(const ushort* __restrict__ h7,
                                                   float* __restrict__ part) {
  int bid = blockIdx.x;                 // NB*8 blocks
  int bgr = bid >> 3, seg = bid & 7;    // 128 rows/segment
  int t = threadIdx.x;
  int rg = t >> 5, cl = t & 31;
  const ushort* hb = h7 + (size_t)bgr * NN * 256;
  float a[8] = {};
  float f[8];
  for (int r = seg * 128 + rg; r < seg * 128 + 128; r += 8) {
    uint4 v = *(const uint4*)&hb[(size_t)r * 256 + cl * 8];
    up8(v, f);
#pragma unroll
    for (int j = 0; j < 8; ++j) a[j] += f[j];
  }
  __shared__ float red[8][256];
#pragma unroll
  for (int j = 0; j < 8; ++j) red[rg][cl * 8 + j] = a[j];
  __syncthreads();
  float s = 0.f;
#pragma unroll
  for (int g = 0; g < 8; ++g) s += red[g][t];
  part[(size_t)bid * 256 + t] = s;
}

__global__ __launch_bounds__(256) void pool_out_k(const float* __restrict__ part,
    const float* __restrict__ Wo, const float* __restrict__ bo, float* __restrict__ out) {
  int bgr = blockIdx.x, t = threadIdx.x;
  float s = 0.f;
#pragma unroll
  for (int g = 0; g < 8; ++g) s += part[(size_t)(bgr * 8 + g) * 256 + t];
  __shared__ float pv[256];
  pv[t] = s;
  __syncthreads();
  if (t < 8) {
    float o = bo[t];
    for (int c = 0; c < 256; ++c) o += pv[c] * Wo[c * 8 + t];
    out[bgr * 8 + t] = o;
  }
}

__global__ void zero_out_k(float* out, int n) {
  int g = blockIdx.x * 256 + threadIdx.x;
  if (g < n) out[g] = 0.f;
}

// ---------------- launch ----------------

extern "C" void kernel_launch(void* const* d_in, const int* in_sizes, int n_in,
                              void* d_out, int out_size, void* d_ws, size_t ws_size,
                              hipStream_t stream) {
  const float* x   = (const float*)d_in[0];
  const int*   ei  = (const int*)d_in[1];
  const float* ew  = (const float*)d_in[2];
  const float* W1  = (const float*)d_in[3];
  const float* b1  = (const float*)d_in[4];
  const float* W2  = (const float*)d_in[5];
  const float* b2  = (const float*)d_in[6];
  const float* W3  = (const float*)d_in[7];
  const float* b3  = (const float*)d_in[8];
  const float* W4  = (const float*)d_in[9];
  const float* b4  = (const float*)d_in[10];
  const float* Wl  = (const float*)d_in[11];
  const float* Wr  = (const float*)d_in[12];
  const float* att = (const float*)d_in[13];
  const float* bg  = (const float*)d_in[14];
  const float* Wg1 = (const float*)d_in[15];
  const float* Wm  = (const float*)d_in[16];
  const float* bm  = (const float*)d_in[17];
  const float* Wg2 = (const float*)d_in[18];
  const float* Wo  = (const float*)d_in[23];
  const float* bo  = (const float*)d_in[24];
  float* out = (float*)d_out;

  const int M = NB * NN;

  char* wp = (char*)d_ws;
  size_t used = 0;
  auto alloc = [&](size_t bytes) -> void* {
    void* p = (void*)wp;
    size_t a = (bytes + 255) & ~(size_t)255;
    wp += a; used += a;
    return p;
  };
  float* dinvw = (float*)alloc((size_t)NB * NN * 4);
  float* dinvu = (float*)alloc((size_t)NB * NN * 4);
  int*   rowptr= (int*)alloc((size_t)NB * (NN + 1) * 4);
  int*   phist = (int*)alloc((size_t)NB * NCH * NN * 4);
  float* pdegw = (float*)alloc((size_t)NB * NCH * NN * 4);
  int2*  peW   = (int2*)alloc((size_t)NB * NE * 8);
  float* part  = (float*)alloc((size_t)NB * 8 * 256 * 4);
  ushort* Wt1  = (ushort*)alloc((size_t)256 * 320 * 2);
  ushort* Wt2  = (ushort*)alloc((size_t)128 * 256 * 2);
  ushort* Wt3  = (ushort*)alloc((size_t)64 * 128 * 2);
  ushort* Wt4  = (ushort*)alloc((size_t)32 * 64 * 2);
  ushort* WtLR = (ushort*)alloc((size_t)256 * 32 * 2);
  ushort* Wtg1 = (ushort*)alloc((size_t)128 * 128 * 2);
  ushort* Wtm  = (ushort*)alloc((size_t)256 * 128 * 2);
  ushort* Wtg2 = (ushort*)alloc((size_t)256 * 256 * 2);
  ushort* B1 = (ushort*)alloc((size_t)M * 256 * 2);   // h1
  ushort* B2 = (ushort*)alloc((size_t)M * 256 * 2);
  ushort* B3 = (ushort*)alloc((size_t)M * 256 * 2);
  ushort* B4 = (ushort*)alloc((size_t)M * 256 * 2);   // xlr
  ushort* B2a = B2, *B2b = B2 + (size_t)M * 128;
  ushort* B3a = B3, *B3b = B3 + (size_t)M * 128;

  if (used > ws_size) {
    zero_out_k<<<(out_size + 255) / 256, 256, 0, stream>>>(out, out_size);
    return;
  }

  // ---- weight conversions ----
  wconv_all_k<<<968, 256, 0, stream>>>(W1, W2, W3, W4, Wl, Wr, Wg1, Wm, Wg2,
                                       Wt1, Wt2, Wt3, Wt4, WtLR, Wtg1, Wtm, Wtg2);

  // ---- CSR build (2-pass counting sort, XCD-affine chunks) ----
  hist_k<<<NB * NCH, 256, 0, stream>>>(ei, ew, phist, pdegw);
  scan2_k<<<NB, 1024, 0, stream>>>(phist, pdegw, dinvw, dinvu, rowptr);
  scatter2_k<<<NB * NCH, 256, 0, stream>>>(ei, ew, phist, dinvw, peW);

  // ---- GCN stack (BM=64 tiles; GEMM1 reads fp32 x directly) ----
  mgemm_k<2,4,0,1><<<dim3(2, M / 64), 256, 0, stream>>>(nullptr, x, Wt1, nullptr, B2, M, 320, 256);
  prop_k<256,0,0><<<M / 8, 256, 0, stream>>>(B2, B1, peW, dinvw, rowptr, b1, nullptr);    // h1
  mgemm_k<2,4,0,0><<<dim3(1, M / 64), 256, 0, stream>>>(B1, nullptr, Wt2, nullptr, B2a, M, 256, 128);
  prop_k<128,0,0><<<M / 16, 256, 0, stream>>>(B2a, B3a, peW, dinvw, rowptr, b2, nullptr); // h2
  mgemm_k<2,2,0,0><<<dim3(1, M / 64), 256, 0, stream>>>(B3a, nullptr, Wt3, nullptr, B2a, M, 128, 64);
  prop_k<64,0,0><<<M / 32, 256, 0, stream>>>(B2a, B3b, peW, dinvw, rowptr, b3, nullptr);  // h3
  mgemm_k<2,1,0,0><<<dim3(1, M / 64), 256, 0, stream>>>(B3b, nullptr, Wt4, nullptr, B2a, M, 64, 32);
  prop_k<32,0,0><<<M / 64, 256, 0, stream>>>(B2a, B2b, peW, dinvw, rowptr, b4, nullptr);  // h4

  // ---- GATv2 (xl|xr one GEMM; fused flash-style attention) ----
  mgemm_k<2,4,0,0><<<dim3(2, M / 64), 256, 0, stream>>>(B2b, nullptr, WtLR, nullptr, B4, M, 32, 256);
  gat_fused_k<<<M / 16, 256, 0, stream>>>(B4, peW, rowptr, att, bg, B2a);                 // hg

  // ---- GCN2Conv #1 (x0 = h2 = B3a) ----
  prop_k<128,1,0><<<M / 16, 256, 0, stream>>>(B2a, B2b, peW, dinvw, rowptr, nullptr, B3a); // z1
  mgemm_k<2,4,2,0><<<dim3(1, M / 64), 256, 0, stream>>>(B2b, nullptr, Wtg1, B2b, B2a, M, 128, 128);

  // ---- GCNConv mid (unweighted norm, on-the-fly du[s]*du[d]) ----
  mgemm_k<2,4,0,0><<<dim3(2, M / 64), 256, 0, stream>>>(B2a, nullptr, Wtm, nullptr, B3, M, 128, 256);
  prop_k<256,0,1><<<M / 8, 256, 0, stream>>>(B3, B2, peW, dinvu, rowptr, bm, nullptr);    // h6

  // ---- GCN2Conv #2 (x0 = h1 = B1) ----
  prop_k<256,1,0><<<M / 8, 256, 0, stream>>>(B2, B3, peW, dinvw, rowptr, nullptr, B1);    // z2
  mgemm_k<2,4,2,0><<<dim3(2, M / 64), 256, 0, stream>>>(B3, nullptr, Wtg2, B3, B2, M, 256, 256);

  // ---- collapsed diff-pool + output projection ----
  pool_part_k<<<NB * 8, 256, 0, stream>>>(B2, part);
  pool_out_k<<<NB, 256, 0, stream>>>(part, Wo, bo, out);
}

// Round 17
// 403.020 us; speedup vs baseline: 1.2707x; 1.0289x over previous
//
#include <hip/hip_runtime.h>
#include <cstdint>
#include <cstddef>

constexpr int NB = 64;     // graphs
constexpr int NN = 1024;   // nodes/graph
constexpr int NE = 16384;  // edges/graph
constexpr int NCH = 16;    // CSR-build chunks per graph
constexpr int CHE = NE / NCH;
constexpr float C_BETA = 0.04879016417f;   // log(0.1/2 + 1)

typedef __attribute__((ext_vector_type(8))) short s8v;   // 8 bf16 (4 VGPRs)
typedef __attribute__((ext_vector_type(4))) float f4v;

__device__ inline float bf2f(ushort u){ union{uint u;float f;} v; v.u=((uint)u)<<16; return v.f; }
__device__ inline ushort f2bf(float f){ union{float f;uint u;} v; v.f=f; uint r=v.u+0x7fffu+((v.u>>16)&1u); return (ushort)(r>>16); }
__device__ inline void up8(uint4 x, float* o){
  o[0]=bf2f((ushort)x.x); o[1]=bf2f((ushort)(x.x>>16));
  o[2]=bf2f((ushort)x.y); o[3]=bf2f((ushort)(x.y>>16));
  o[4]=bf2f((ushort)x.z); o[5]=bf2f((ushort)(x.z>>16));
  o[6]=bf2f((ushort)x.w); o[7]=bf2f((ushort)(x.w>>16));
}
__device__ inline uint pk2(float a, float b){ return (uint)f2bf(a) | ((uint)f2bf(b)<<16); }
__device__ inline uint4 pk8(const float* f){
  uint4 v; v.x=pk2(f[0],f[1]); v.y=pk2(f[2],f[3]); v.z=pk2(f[4],f[5]); v.w=pk2(f[6],f[7]); return v;
}
// XCD-bijective swizzle: requires grid = NB*bpg, NB=64
__device__ inline int swz8(int bid, int bpg){
  int xcd = bid & 7, j = bid >> 3;
  return (xcd * (NB/8) + j / bpg) * bpg + (j % bpg);
}

// ---------------- CSR build: 2-pass counting sort, full-GPU width ----------------
// Block mapping b = blk&63, ch = blk>>6: all chunks of graph b share XCD b%8.

__global__ __launch_bounds__(256) void hist_k(const int* __restrict__ ei,
    const float* __restrict__ ew, int* __restrict__ phist, float* __restrict__ pdegw) {
  int blk = blockIdx.x;               // NB*NCH
  int b = blk & 63, ch = blk >> 6;
  __shared__ int hc[NN];
  __shared__ float hw[NN];
  int t = threadIdx.x;
  for (int i = t; i < NN; i += 256) { hc[i] = 0; hw[i] = 0.f; }
  __syncthreads();
  const int* dstb = ei + (size_t)b * 2 * NE + NE + ch * CHE;
  const float* ewb = ew + (size_t)b * NE + ch * CHE;
  for (int e = t; e < CHE; e += 256) {
    int d = dstb[e];
    atomicAdd(&hc[d], 1);
    atomicAdd(&hw[d], ewb[e]);
  }
  __syncthreads();
  size_t o = ((size_t)b * NCH + ch) * NN;
  for (int i = t; i < NN; i += 256) {
    phist[o + i] = hc[i];
    pdegw[o + i] = hw[i];
  }
}

__global__ __launch_bounds__(1024) void scan2_k(int* __restrict__ phist,
    const float* __restrict__ pdegw, float* __restrict__ dinvw,
    float* __restrict__ dinvu, int* __restrict__ rowptr) {
  int b = blockIdx.x, t = threadIdx.x;
  size_t base = (size_t)b * NCH * NN;
  int h[NCH];
  int cnt = 0; float dw = 1.0f;   // self-loop weight 1
#pragma unroll
  for (int c = 0; c < NCH; ++c) {
    h[c] = phist[base + c * NN + t];
    cnt += h[c];
    dw += pdegw[base + c * NN + t];
  }
  dinvw[b * NN + t] = rsqrtf(dw);
  dinvu[b * NN + t] = rsqrtf(1.0f + (float)cnt);
  __shared__ int ss[NN];
  ss[t] = cnt;
  __syncthreads();
  for (int off = 1; off < NN; off <<= 1) {
    int xv = (t >= off) ? ss[t - off] : 0;
    __syncthreads();
    ss[t] += xv;
    __syncthreads();
  }
  rowptr[b * (NN + 1) + t + 1] = ss[t];
  if (t == 0) rowptr[b * (NN + 1)] = 0;
  int excl = ss[t] - cnt;
#pragma unroll
  for (int c = 0; c < NCH; ++c) {
    phist[base + c * NN + t] = excl;
    excl += h[c];
  }
}

// scatter: single packed array {src, wn}; unweighted norm recomputed on the fly in prop.
__global__ __launch_bounds__(256) void scatter2_k(const int* __restrict__ ei,
    const float* __restrict__ ew, const int* __restrict__ coff,
    const float* __restrict__ dinvw, int2* __restrict__ peW) {
  int blk = blockIdx.x;
  int b = blk & 63, ch = blk >> 6;
  __shared__ int sbase[NN];
  __shared__ int sfill[NN];
  __shared__ float sdw[NN];
  int t = threadIdx.x;
  for (int i = t; i < NN; i += 256) {
    sbase[i] = coff[((size_t)b * NCH + ch) * NN + i];
    sfill[i] = 0;
    sdw[i] = dinvw[b * NN + i];
  }
  __syncthreads();
  const int* srcb = ei + (size_t)b * 2 * NE + ch * CHE;
  const int* dstb = ei + (size_t)b * 2 * NE + NE + ch * CHE;
  const float* ewb = ew + (size_t)b * NE + ch * CHE;
  int2* pwb = peW + (size_t)b * NE;
  for (int e = t; e < CHE; e += 256) {
    int s = srcb[e], d = dstb[e];
    int pos = sbase[d] + atomicAdd(&sfill[d], 1);
    pwb[pos] = make_int2(s, __float_as_int(sdw[s] * ewb[e] * sdw[d]));
  }
}

// ---------------- weight conversions ----------------

__device__ inline void wcv(const float* __restrict__ W, ushort* __restrict__ Wt,
                           int idx, int K, int N, int Kp) {
  int n = idx / Kp, k = idx % Kp;
  Wt[idx] = (k < K) ? f2bf(W[(size_t)k * N + n]) : (ushort)0;
}

__global__ void wconv_all_k(const float* W1, const float* W2, const float* W3,
                            const float* W4, const float* Wl, const float* Wr,
                            const float* Wg1, const float* Wm, const float* Wg2,
                            ushort* Wt1, ushort* Wt2, ushort* Wt3, ushort* Wt4,
                            ushort* WtLR, ushort* Wtg1, ushort* Wtm, ushort* Wtg2) {
  int bb = blockIdx.x, t = threadIdx.x;
  if      (bb < 320) wcv(W1, Wt1, bb * 256 + t, 300, 256, 320);
  else if (bb < 448) wcv(W2, Wt2, (bb - 320) * 256 + t, 256, 128, 256);
  else if (bb < 480) wcv(W3, Wt3, (bb - 448) * 256 + t, 128, 64, 128);
  else if (bb < 488) wcv(W4, Wt4, (bb - 480) * 256 + t, 64, 32, 64);
  else if (bb < 504) wcv(Wl, WtLR, (bb - 488) * 256 + t, 32, 128, 32);
  else if (bb < 520) wcv(Wr, WtLR + 128 * 32, (bb - 504) * 256 + t, 32, 128, 32);
  else if (bb < 584) wcv(Wg1, Wtg1, (bb - 520) * 256 + t, 128, 128, 128);
  else if (bb < 712) wcv(Wm, Wtm, (bb - 584) * 256 + t, 128, 256, 128);
  else               wcv(Wg2, Wtg2, (bb - 712) * 256 + t, 256, 256, 256);
}

// ---------------- MFMA bf16 GEMM, register-prefetch pipeline (no arrays across barriers) ----
// BM = WR*32 = 64 exactly (A chunks == 256 == one per thread).
// Per iter: commit staged regs->LDS, barrier, ISSUE k+1 loads, MFMA, barrier.
// AF32: A fp32 row-stride 300, converted during commit.  MODE 2: GCN2 epilogue.

template<int WR, int NI, int MODE, int AF32>
__global__ __launch_bounds__(256) void mgemm_k(const ushort* __restrict__ A,
    const float* __restrict__ Af, const ushort* __restrict__ Bt,
    const ushort* __restrict__ Z, ushort* __restrict__ C, int M, int K, int N) {
  constexpr int BM = WR * 32;      // 64
  constexpr int BN = NI * 32;
  constexpr int KR = 300;
  constexpr int BCH = BN * 4;      // B 16B-chunks total (128/256/512)
  __shared__ ushort As[BM][40];
  __shared__ ushort Bs[BN][40];
  int tid = threadIdx.x;
  int wave = tid >> 6, lane = tid & 63;
  int bm = blockIdx.y * BM, bn = blockIdx.x * BN;
  int wm = (wave >> 1) * (WR * 16), wn = (wave & 1) * (NI * 16);
  f4v acc[WR][NI];
#pragma unroll
  for (int a = 0; a < WR; ++a)
#pragma unroll
    for (int b = 0; b < NI; ++b)
#pragma unroll
      for (int q = 0; q < 4; ++q) acc[a][b][q] = 0.f;

  int arow = tid >> 2, akc = (tid & 3) * 8;               // A chunk (1/thread)
  int b0row = tid >> 2, b0kc = (tid & 3) * 8;             // B chunk tid (if tid<BCH)
  int b1row = (256 + tid) >> 2, b1kc = ((256 + tid) & 3) * 8;  // B chunk tid+256

  float fa[8];     // AF32 staged A (static indices only)
  uint4 paw;       // bf16 staged A
  uint4 pb0, pb1;  // staged B

  // ---- prologue: load k0 = 0 ----
  if (AF32) {
    const float* xr = Af + (size_t)(bm + arow) * KR + akc;
    if (akc + 8 <= KR) {
      float4 q1 = *(const float4*)xr, q2 = *(const float4*)(xr + 4);
      fa[0]=q1.x; fa[1]=q1.y; fa[2]=q1.z; fa[3]=q1.w;
      fa[4]=q2.x; fa[5]=q2.y; fa[6]=q2.z; fa[7]=q2.w;
    } else {
#pragma unroll
      for (int j = 0; j < 8; ++j) fa[j] = (akc + j < KR) ? xr[j] : 0.f;
    }
  } else {
    paw = *(const uint4*)&A[(size_t)(bm + arow) * K + akc];
  }
  if (tid < BCH) pb0 = *(const uint4*)&Bt[(size_t)(bn + b0row) * K + b0kc];
  if (BCH > 256) pb1 = *(const uint4*)&Bt[(size_t)(bn + b1row) * K + b1kc];

  int r = lane & 15, kg = (lane >> 4) * 8;
  for (int k0 = 0; k0 < K; k0 += 32) {
    // commit staged regs to LDS (vmcnt wait lands here)
    if (AF32) *(uint4*)&As[arow][akc] = pk8(fa);
    else      *(uint4*)&As[arow][akc] = paw;
    if (tid < BCH) *(uint4*)&Bs[b0row][b0kc] = pb0;
    if (BCH > 256) *(uint4*)&Bs[b1row][b1kc] = pb1;
    __syncthreads();
    int kn = k0 + 32;
    if (kn < K) {   // issue next-tile loads; in flight across MFMA + barrier
      if (AF32) {
        const float* xr = Af + (size_t)(bm + arow) * KR + kn + akc;
        if (kn + akc + 8 <= KR) {
          float4 q1 = *(const float4*)xr, q2 = *(const float4*)(xr + 4);
          fa[0]=q1.x; fa[1]=q1.y; fa[2]=q1.z; fa[3]=q1.w;
          fa[4]=q2.x; fa[5]=q2.y; fa[6]=q2.z; fa[7]=q2.w;
        } else {
#pragma unroll
          for (int j = 0; j < 8; ++j) fa[j] = (kn + akc + j < KR) ? xr[j] : 0.f;
        }
      } else {
        paw = *(const uint4*)&A[(size_t)(bm + arow) * K + kn + akc];
      }
      if (tid < BCH) pb0 = *(const uint4*)&Bt[(size_t)(bn + b0row) * K + kn + b0kc];
      if (BCH > 256) pb1 = *(const uint4*)&Bt[(size_t)(bn + b1row) * K + kn + b1kc];
    }
    s8v af[WR], bf[NI];
#pragma unroll
    for (int mi = 0; mi < WR; ++mi) af[mi] = *(const s8v*)&As[wm + mi * 16 + r][kg];
#pragma unroll
    for (int ni = 0; ni < NI; ++ni) bf[ni] = *(const s8v*)&Bs[wn + ni * 16 + r][kg];
#pragma unroll
    for (int mi = 0; mi < WR; ++mi)
#pragma unroll
      for (int ni = 0; ni < NI; ++ni)
        acc[mi][ni] = __builtin_amdgcn_mfma_f32_16x16x32_bf16(af[mi], bf[ni], acc[mi][ni], 0, 0, 0);
    __syncthreads();
  }
  int col = lane & 15, rowg = (lane >> 4) * 4;
#pragma unroll
  for (int mi = 0; mi < WR; ++mi)
#pragma unroll
    for (int ni = 0; ni < NI; ++ni)
#pragma unroll
      for (int q = 0; q < 4; ++q) {
        int row = bm + wm + mi * 16 + rowg + q;
        int cc = bn + wn + ni * 16 + col;
        size_t idx = (size_t)row * N + cc;
        float v = acc[mi][ni][q];
        if (MODE == 2) v = fmaxf((1.f - C_BETA) * bf2f(Z[idx]) + C_BETA * v, 0.f);
        C[idx] = f2bf(v);
      }
}

// ---------------- graph propagation (packed dst-CSR gather via L2, bf16 I/O) ----------------
// acc = dinv[i]^2*in[i,:] + sum_p w[p]*in[src[p],:]
// WSEL 0: w = pe.y.  WSEL 1: w = dinv[s]*dinv[i] (on-the-fly).
// MODE 0: out = relu(acc + bias).  MODE 1: out = 0.5*acc + 0.5*x0.

template<int D, int MODE, int WSEL>
__global__ __launch_bounds__(256) void prop_k(const ushort* __restrict__ in,
    ushort* __restrict__ out, const int2* __restrict__ pedge,
    const float* __restrict__ dinv, const int* __restrict__ rowptr,
    const float* __restrict__ bias, const ushort* __restrict__ x0) {
  constexpr int TPN = D / 8, NPB = 256 / TPN, BPG = NN / NPB;
  int t = threadIdx.x;
  int bid = swz8(blockIdx.x, BPG);
  int tn = t / TPN, cl = t % TPN;
  int node = bid * NPB + tn;
  int b = node >> 10, i = node & 1023;
  float di = dinv[node];
  float f[8], acc[8];
  uint4 ov = *(const uint4*)&in[(size_t)node * D + cl * 8];
  up8(ov, f);
  float w0 = di * di;
#pragma unroll
  for (int j = 0; j < 8; ++j) acc[j] = w0 * f[j];
  int r0 = rowptr[b * (NN + 1) + i], r1 = rowptr[b * (NN + 1) + i + 1];
  const int2* pe = pedge + (size_t)b * NE;
  const float* dvb = dinv + b * NN;
  const ushort* inb = in + (size_t)b * NN * D;
  int p = r0;
  for (; p + 4 <= r1; p += 4) {      // 4-way unroll: independent loads
    int2 e0 = pe[p], e1 = pe[p + 1], e2 = pe[p + 2], e3 = pe[p + 3];
    float wa, wb2, wc, wd;
    if (WSEL == 0) {
      wa = __int_as_float(e0.y); wb2 = __int_as_float(e1.y);
      wc = __int_as_float(e2.y); wd = __int_as_float(e3.y);
    } else {
      wa = dvb[e0.x] * di; wb2 = dvb[e1.x] * di;
      wc = dvb[e2.x] * di; wd = dvb[e3.x] * di;
    }
    uint4 rv0 = *(const uint4*)&inb[(size_t)e0.x * D + cl * 8];
    uint4 rv1 = *(const uint4*)&inb[(size_t)e1.x * D + cl * 8];
    uint4 rv2 = *(const uint4*)&inb[(size_t)e2.x * D + cl * 8];
    uint4 rv3 = *(const uint4*)&inb[(size_t)e3.x * D + cl * 8];
    up8(rv0, f);
#pragma unroll
    for (int j = 0; j < 8; ++j) acc[j] += wa * f[j];
    up8(rv1, f);
#pragma unroll
    for (int j = 0; j < 8; ++j) acc[j] += wb2 * f[j];
    up8(rv2, f);
#pragma unroll
    for (int j = 0; j < 8; ++j) acc[j] += wc * f[j];
    up8(rv3, f);
#pragma unroll
    for (int j = 0; j < 8; ++j) acc[j] += wd * f[j];
  }
  for (; p < r1; ++p) {
    int2 e = pe[p];
    float w = (WSEL == 0) ? __int_as_float(e.y) : dvb[e.x] * di;
    uint4 rv = *(const uint4*)&inb[(size_t)e.x * D + cl * 8];
    up8(rv, f);
#pragma unroll
    for (int j = 0; j < 8; ++j) acc[j] += w * f[j];
  }
  size_t ob = (size_t)node * D + cl * 8;
  if (MODE == 0) {
#pragma unroll
    for (int j = 0; j < 8; ++j) acc[j] = fmaxf(acc[j] + bias[cl * 8 + j], 0.f);
  } else {
    uint4 xv = *(const uint4*)&x0[ob];
    up8(xv, f);
#pragma unroll
    for (int j = 0; j < 8; ++j) acc[j] = 0.5f * acc[j] + 0.5f * f[j];
  }
  *(uint4*)&out[ob] = pk8(acc);
}

// ---------------- GATv2: fused flash-style with defer-max ----------------
// xlr layout: [node][256]: ch 0-127 = xl, 128-255 = xr.

#define GAT_UPD(P, FL)                                            \
  if (P > m + 8.f) {               /* rare: rescale */            \
    float sc = __expf(m - P);                                     \
    den *= sc;                                                    \
    _Pragma("unroll")                                             \
    for (int j = 0; j < 8; ++j) acc[j] *= sc;                     \
    m = P;                                                        \
    den += 1.f;                                                   \
    _Pragma("unroll")                                             \
    for (int j = 0; j < 8; ++j) acc[j] += FL[j];                  \
  } else {                                                        \
    float ex = __expf(P - m);                                     \
    den += ex;                                                    \
    _Pragma("unroll")                                             \
    for (int j = 0; j < 8; ++j) acc[j] += ex * FL[j];             \
  }

__global__ __launch_bounds__(256) void gat_fused_k(const ushort* __restrict__ xlr,
    const int2* __restrict__ pedge, const int* __restrict__ rowptr,
    const float* __restrict__ att, const float* __restrict__ bg,
    ushort* __restrict__ out) {
  int bid = swz8(blockIdx.x, NN / 16);   // 16 nodes/block
  int t = threadIdx.x;
  int tn = t >> 4, cl = t & 15;
  int node = bid * 16 + tn;
  int b = node >> 10, i = node & 1023;
  int ch = cl * 8;
  int r0 = rowptr[b * (NN + 1) + i], r1 = rowptr[b * (NN + 1) + i + 1];
  const ushort* xb = xlr + (size_t)b * NN * 256;
  const int2* pe = pedge + (size_t)b * NE;
  float fr[8], at[8];
  {
    uint4 rv = *(const uint4*)&xb[(size_t)i * 256 + 128 + ch];  // xr[i] chunk
    up8(rv, fr);
#pragma unroll
    for (int j = 0; j < 8; ++j) at[j] = att[ch + j];
  }
  float m, den, acc[8];
  {
    float fs[8];
    uint4 sv = *(const uint4*)&xb[(size_t)i * 256 + ch];        // xl[i] (self)
    up8(sv, fs);
    float part = 0.f;
#pragma unroll
    for (int j = 0; j < 8; ++j) {
      float v = fs[j] + fr[j];
      part += fmaxf(v, 0.2f * v) * at[j];
    }
    part += __shfl_xor(part, 1);
    part += __shfl_xor(part, 2);
    m = part; den = 1.f;
#pragma unroll
    for (int j = 0; j < 8; ++j) acc[j] = fs[j];
  }
  float fl0[8], fl1[8];
  int p = r0;
  for (; p + 2 <= r1; p += 2) {
    int s0 = pe[p].x, s1 = pe[p + 1].x;
    uint4 v0 = *(const uint4*)&xb[(size_t)s0 * 256 + ch];
    uint4 v1 = *(const uint4*)&xb[(size_t)s1 * 256 + ch];
    up8(v0, fl0); up8(v1, fl1);
    float p0 = 0.f, p1 = 0.f;
#pragma unroll
    for (int j = 0; j < 8; ++j) {
      float a0 = fl0[j] + fr[j];
      float a1 = fl1[j] + fr[j];
      p0 += fmaxf(a0, 0.2f * a0) * at[j];
      p1 += fmaxf(a1, 0.2f * a1) * at[j];
    }
    p0 += __shfl_xor(p0, 1); p0 += __shfl_xor(p0, 2);
    p1 += __shfl_xor(p1, 1); p1 += __shfl_xor(p1, 2);
    GAT_UPD(p0, fl0)
    GAT_UPD(p1, fl1)
  }
  if (p < r1) {
    int s = pe[p].x;
    uint4 v0 = *(const uint4*)&xb[(size_t)s * 256 + ch];
    up8(v0, fl0);
    float p0 = 0.f;
#pragma unroll
    for (int j = 0; j < 8; ++j) {
      float a0 = fl0[j] + fr[j];
      p0 += fmaxf(a0, 0.2f * a0) * at[j];
    }
    p0 += __shfl_xor(p0, 1); p0 += __shfl_xor(p0, 2);
    GAT_UPD(p0, fl0)
  }
  float inv = 1.f / den;
#pragma unroll
  for (int j = 0; j < 8; ++j) acc[j] = fmaxf(acc[j] * inv + bg[ch + j], 0.f);
  *(uint4*)&out[(size_t)node * 128 + ch] = pk8(acc);
}

// ---------------- pooled = column-sum(h7); out = pooled @ Wo + bo ----------------

__global__ __launch_bounds__(256) void pool_part_k(const ushort* __restrict__ h7,
                                                   float* __restrict__ part) {
  int bid = blockIdx.x;                 // NB*8 blocks
  int bgr = bid >> 3, seg = bid & 7;    // 128 rows/segment
  int t = threadIdx.x;
  int rg = t >> 5, cl = t & 31;
  const ushort* hb = h7 + (size_t)bgr * NN * 256;
  float a[8] = {};
  float f[8];
  for (int r = seg * 128 + rg; r < seg * 128 + 128; r += 8) {
    uint4 v = *(const uint4*)&hb[(size_t)r * 256 + cl * 8];
    up8(v, f);
#pragma unroll
    for (int j = 0; j < 8; ++j) a[j] += f[j];
  }
  __shared__ float red[8][256];
#pragma unroll
  for (int j = 0; j < 8; ++j) red[rg][cl * 8 + j] = a[j];
  __syncthreads();
  float s = 0.f;
#pragma unroll
  for (int g = 0; g < 8; ++g) s += red[g][t];
  part[(size_t)bid * 256 + t] = s;
}

__global__ __launch_bounds__(256) void pool_out_k(const float* __restrict__ part,
    const float* __restrict__ Wo, const float* __restrict__ bo, float* __restrict__ out) {
  int bgr = blockIdx.x, t = threadIdx.x;
  float s = 0.f;
#pragma unroll
  for (int g = 0; g < 8; ++g) s += part[(size_t)(bgr * 8 + g) * 256 + t];
  __shared__ float pv[256];
  pv[t] = s;
  __syncthreads();
  if (t < 8) {
    float o = bo[t];
    for (int c = 0; c < 256; ++c) o += pv[c] * Wo[c * 8 + t];
    out[bgr * 8 + t] = o;
  }
}

__global__ void zero_out_k(float* out, int n) {
  int g = blockIdx.x * 256 + threadIdx.x;
  if (g < n) out[g] = 0.f;
}

// ---------------- launch ----------------

extern "C" void kernel_launch(void* const* d_in, const int* in_sizes, int n_in,
                              void* d_out, int out_size, void* d_ws, size_t ws_size,
                              hipStream_t stream) {
  const float* x   = (const float*)d_in[0];
  const int*   ei  = (const int*)d_in[1];
  const float* ew  = (const float*)d_in[2];
  const float* W1  = (const float*)d_in[3];
  const float* b1  = (const float*)d_in[4];
  const float* W2  = (const float*)d_in[5];
  const float* b2  = (const float*)d_in[6];
  const float* W3  = (const float*)d_in[7];
  const float* b3  = (const float*)d_in[8];
  const float* W4  = (const float*)d_in[9];
  const float* b4  = (const float*)d_in[10];
  const float* Wl  = (const float*)d_in[11];
  const float* Wr  = (const float*)d_in[12];
  const float* att = (const float*)d_in[13];
  const float* bg  = (const float*)d_in[14];
  const float* Wg1 = (const float*)d_in[15];
  const float* Wm  = (const float*)d_in[16];
  const float* bm  = (const float*)d_in[17];
  const float* Wg2 = (const float*)d_in[18];
  const float* Wo  = (const float*)d_in[23];
  const float* bo  = (const float*)d_in[24];
  float* out = (float*)d_out;

  const int M = NB * NN;

  char* wp = (char*)d_ws;
  size_t used = 0;
  auto alloc = [&](size_t bytes) -> void* {
    void* p = (void*)wp;
    size_t a = (bytes + 255) & ~(size_t)255;
    wp += a; used += a;
    return p;
  };
  float* dinvw = (float*)alloc((size_t)NB * NN * 4);
  float* dinvu = (float*)alloc((size_t)NB * NN * 4);
  int*   rowptr= (int*)alloc((size_t)NB * (NN + 1) * 4);
  int*   phist = (int*)alloc((size_t)NB * NCH * NN * 4);
  float* pdegw = (float*)alloc((size_t)NB * NCH * NN * 4);
  int2*  peW   = (int2*)alloc((size_t)NB * NE * 8);
  float* part  = (float*)alloc((size_t)NB * 8 * 256 * 4);
  ushort* Wt1  = (ushort*)alloc((size_t)256 * 320 * 2);
  ushort* Wt2  = (ushort*)alloc((size_t)128 * 256 * 2);
  ushort* Wt3  = (ushort*)alloc((size_t)64 * 128 * 2);
  ushort* Wt4  = (ushort*)alloc((size_t)32 * 64 * 2);
  ushort* WtLR = (ushort*)alloc((size_t)256 * 32 * 2);
  ushort* Wtg1 = (ushort*)alloc((size_t)128 * 128 * 2);
  ushort* Wtm  = (ushort*)alloc((size_t)256 * 128 * 2);
  ushort* Wtg2 = (ushort*)alloc((size_t)256 * 256 * 2);
  ushort* B1 = (ushort*)alloc((size_t)M * 256 * 2);   // h1
  ushort* B2 = (ushort*)alloc((size_t)M * 256 * 2);
  ushort* B3 = (ushort*)alloc((size_t)M * 256 * 2);
  ushort* B4 = (ushort*)alloc((size_t)M * 256 * 2);   // xlr
  ushort* B2a = B2, *B2b = B2 + (size_t)M * 128;
  ushort* B3a = B3, *B3b = B3 + (size_t)M * 128;

  if (used > ws_size) {
    zero_out_k<<<(out_size + 255) / 256, 256, 0, stream>>>(out, out_size);
    return;
  }

  // ---- weight conversions ----
  wconv_all_k<<<968, 256, 0, stream>>>(W1, W2, W3, W4, Wl, Wr, Wg1, Wm, Wg2,
                                       Wt1, Wt2, Wt3, Wt4, WtLR, Wtg1, Wtm, Wtg2);

  // ---- CSR build (2-pass counting sort, XCD-affine chunks) ----
  hist_k<<<NB * NCH, 256, 0, stream>>>(ei, ew, phist, pdegw);
  scan2_k<<<NB, 1024, 0, stream>>>(phist, pdegw, dinvw, dinvu, rowptr);
  scatter2_k<<<NB * NCH, 256, 0, stream>>>(ei, ew, phist, dinvw, peW);

  // ---- GCN stack (BM=64 tiles; GEMM1 reads fp32 x directly) ----
  mgemm_k<2,4,0,1><<<dim3(2, M / 64), 256, 0, stream>>>(nullptr, x, Wt1, nullptr, B2, M, 320, 256);
  prop_k<256,0,0><<<M / 8, 256, 0, stream>>>(B2, B1, peW, dinvw, rowptr, b1, nullptr);    // h1
  mgemm_k<2,4,0,0><<<dim3(1, M / 64), 256, 0, stream>>>(B1, nullptr, Wt2, nullptr, B2a, M, 256, 128);
  prop_k<128,0,0><<<M / 16, 256, 0, stream>>>(B2a, B3a, peW, dinvw, rowptr, b2, nullptr); // h2
  mgemm_k<2,2,0,0><<<dim3(1, M / 64), 256, 0, stream>>>(B3a, nullptr, Wt3, nullptr, B2a, M, 128, 64);
  prop_k<64,0,0><<<M / 32, 256, 0, stream>>>(B2a, B3b, peW, dinvw, rowptr, b3, nullptr);  // h3
  mgemm_k<2,1,0,0><<<dim3(1, M / 64), 256, 0, stream>>>(B3b, nullptr, Wt4, nullptr, B2a, M, 64, 32);
  prop_k<32,0,0><<<M / 64, 256, 0, stream>>>(B2a, B2b, peW, dinvw, rowptr, b4, nullptr);  // h4

  // ---- GATv2 (xl|xr one GEMM; fused flash-style attention) ----
  mgemm_k<2,4,0,0><<<dim3(2, M / 64), 256, 0, stream>>>(B2b, nullptr, WtLR, nullptr, B4, M, 32, 256);
  gat_fused_k<<<M / 16, 256, 0, stream>>>(B4, peW, rowptr, att, bg, B2a);                 // hg

  // ---- GCN2Conv #1 (x0 = h2 = B3a) ----
  prop_k<128,1,0><<<M / 16, 256, 0, stream>>>(B2a, B2b, peW, dinvw, rowptr, nullptr, B3a); // z1
  mgemm_k<2,4,2,0><<<dim3(1, M / 64), 256, 0, stream>>>(B2b, nullptr, Wtg1, B2b, B2a, M, 128, 128);

  // ---- GCNConv mid (unweighted norm, on-the-fly du[s]*du[d]) ----
  mgemm_k<2,4,0,0><<<dim3(2, M / 64), 256, 0, stream>>>(B2a, nullptr, Wtm, nullptr, B3, M, 128, 256);
  prop_k<256,0,1><<<M / 8, 256, 0, stream>>>(B3, B2, peW, dinvu, rowptr, bm, nullptr);    // h6

  // ---- GCN2Conv #2 (x0 = h1 = B1) ----
  prop_k<256,1,0><<<M / 8, 256, 0, stream>>>(B2, B3, peW, dinvw, rowptr, nullptr, B1);    // z2
  mgemm_k<2,4,2,0><<<dim3(2, M / 64), 256, 0, stream>>>(B3, nullptr, Wtg2, B3, B2, M, 256, 256);

  // ---- collapsed diff-pool + output projection ----
  pool_part_k<<<NB * 8, 256, 0, stream>>>(B2, part);
  pool_out_k<<<NB, 256, 0, stream>>>(part, Wo, bo, out);
}

// Round 18
// 401.240 us; speedup vs baseline: 1.2764x; 1.0044x over previous
//
#include <hip/hip_runtime.h>
#include <cstdint>
#include <cstddef>

constexpr int NB = 64;     // graphs
constexpr int NN = 1024;   // nodes/graph
constexpr int NE = 16384;  // edges/graph
constexpr int NCH = 16;    // CSR-build chunks per graph
constexpr int CHE = NE / NCH;
constexpr float C_BETA = 0.04879016417f;   // log(0.1/2 + 1)

typedef __attribute__((ext_vector_type(8))) short s8v;   // 8 bf16 (4 VGPRs)
typedef __attribute__((ext_vector_type(4))) float f4v;

__device__ inline float bf2f(ushort u){ union{uint u;float f;} v; v.u=((uint)u)<<16; return v.f; }
__device__ inline ushort f2bf(float f){ union{float f;uint u;} v; v.f=f; uint r=v.u+0x7fffu+((v.u>>16)&1u); return (ushort)(r>>16); }
__device__ inline void up8(uint4 x, float* o){
  o[0]=bf2f((ushort)x.x); o[1]=bf2f((ushort)(x.x>>16));
  o[2]=bf2f((ushort)x.y); o[3]=bf2f((ushort)(x.y>>16));
  o[4]=bf2f((ushort)x.z); o[5]=bf2f((ushort)(x.z>>16));
  o[6]=bf2f((ushort)x.w); o[7]=bf2f((ushort)(x.w>>16));
}
__device__ inline uint pk2(float a, float b){ return (uint)f2bf(a) | ((uint)f2bf(b)<<16); }
__device__ inline uint4 pk8(const float* f){
  uint4 v; v.x=pk2(f[0],f[1]); v.y=pk2(f[2],f[3]); v.z=pk2(f[4],f[5]); v.w=pk2(f[6],f[7]); return v;
}
// XCD-bijective swizzle: requires grid = NB*bpg, NB=64
__device__ inline int swz8(int bid, int bpg){
  int xcd = bid & 7, j = bid >> 3;
  return (xcd * (NB/8) + j / bpg) * bpg + (j % bpg);
}

// ---------------- CSR build: 2-pass counting sort, full-GPU width ----------------
// Block mapping b = blk&63, ch = blk>>6: all chunks of graph b share XCD b%8.

__global__ __launch_bounds__(256) void hist_k(const int* __restrict__ ei,
    const float* __restrict__ ew, int* __restrict__ phist, float* __restrict__ pdegw) {
  int blk = blockIdx.x;               // NB*NCH
  int b = blk & 63, ch = blk >> 6;
  __shared__ int hc[NN];
  __shared__ float hw[NN];
  int t = threadIdx.x;
  for (int i = t; i < NN; i += 256) { hc[i] = 0; hw[i] = 0.f; }
  __syncthreads();
  const int* dstb = ei + (size_t)b * 2 * NE + NE + ch * CHE;
  const float* ewb = ew + (size_t)b * NE + ch * CHE;
  for (int e = t; e < CHE; e += 256) {
    int d = dstb[e];
    atomicAdd(&hc[d], 1);
    atomicAdd(&hw[d], ewb[e]);
  }
  __syncthreads();
  size_t o = ((size_t)b * NCH + ch) * NN;
  for (int i = t; i < NN; i += 256) {
    phist[o + i] = hc[i];
    pdegw[o + i] = hw[i];
  }
}

__global__ __launch_bounds__(1024) void scan2_k(int* __restrict__ phist,
    const float* __restrict__ pdegw, float* __restrict__ dinvw,
    float* __restrict__ dinvu, int* __restrict__ rowptr) {
  int b = blockIdx.x, t = threadIdx.x;
  size_t base = (size_t)b * NCH * NN;
  int h[NCH];
  int cnt = 0; float dw = 1.0f;   // self-loop weight 1
#pragma unroll
  for (int c = 0; c < NCH; ++c) {
    h[c] = phist[base + c * NN + t];
    cnt += h[c];
    dw += pdegw[base + c * NN + t];
  }
  dinvw[b * NN + t] = rsqrtf(dw);
  dinvu[b * NN + t] = rsqrtf(1.0f + (float)cnt);
  __shared__ int ss[NN];
  ss[t] = cnt;
  __syncthreads();
  for (int off = 1; off < NN; off <<= 1) {
    int xv = (t >= off) ? ss[t - off] : 0;
    __syncthreads();
    ss[t] += xv;
    __syncthreads();
  }
  rowptr[b * (NN + 1) + t + 1] = ss[t];
  if (t == 0) rowptr[b * (NN + 1)] = 0;
  int excl = ss[t] - cnt;
#pragma unroll
  for (int c = 0; c < NCH; ++c) {
    phist[base + c * NN + t] = excl;
    excl += h[c];
  }
}

// scatter: single packed array {src, wn}; unweighted norm recomputed on the fly in prop.
__global__ __launch_bounds__(256) void scatter2_k(const int* __restrict__ ei,
    const float* __restrict__ ew, const int* __restrict__ coff,
    const float* __restrict__ dinvw, int2* __restrict__ peW) {
  int blk = blockIdx.x;
  int b = blk & 63, ch = blk >> 6;
  __shared__ int sbase[NN];
  __shared__ int sfill[NN];
  __shared__ float sdw[NN];
  int t = threadIdx.x;
  for (int i = t; i < NN; i += 256) {
    sbase[i] = coff[((size_t)b * NCH + ch) * NN + i];
    sfill[i] = 0;
    sdw[i] = dinvw[b * NN + i];
  }
  __syncthreads();
  const int* srcb = ei + (size_t)b * 2 * NE + ch * CHE;
  const int* dstb = ei + (size_t)b * 2 * NE + NE + ch * CHE;
  const float* ewb = ew + (size_t)b * NE + ch * CHE;
  int2* pwb = peW + (size_t)b * NE;
  for (int e = t; e < CHE; e += 256) {
    int s = srcb[e], d = dstb[e];
    int pos = sbase[d] + atomicAdd(&sfill[d], 1);
    pwb[pos] = make_int2(s, __float_as_int(sdw[s] * ewb[e] * sdw[d]));
  }
}

// ---------------- weight conversions ----------------

__device__ inline void wcv(const float* __restrict__ W, ushort* __restrict__ Wt,
                           int idx, int K, int N, int Kp) {
  int n = idx / Kp, k = idx % Kp;
  Wt[idx] = (k < K) ? f2bf(W[(size_t)k * N + n]) : (ushort)0;
}

__global__ void wconv_all_k(const float* W1, const float* W2, const float* W3,
                            const float* W4, const float* Wl, const float* Wr,
                            const float* Wg1, const float* Wm, const float* Wg2,
                            ushort* Wt1, ushort* Wt2, ushort* Wt3, ushort* Wt4,
                            ushort* WtLR, ushort* Wtg1, ushort* Wtm, ushort* Wtg2) {
  int bb = blockIdx.x, t = threadIdx.x;
  if      (bb < 320) wcv(W1, Wt1, bb * 256 + t, 300, 256, 320);
  else if (bb < 448) wcv(W2, Wt2, (bb - 320) * 256 + t, 256, 128, 256);
  else if (bb < 480) wcv(W3, Wt3, (bb - 448) * 256 + t, 128, 64, 128);
  else if (bb < 488) wcv(W4, Wt4, (bb - 480) * 256 + t, 64, 32, 64);
  else if (bb < 504) wcv(Wl, WtLR, (bb - 488) * 256 + t, 32, 128, 32);
  else if (bb < 520) wcv(Wr, WtLR + 128 * 32, (bb - 504) * 256 + t, 32, 128, 32);
  else if (bb < 584) wcv(Wg1, Wtg1, (bb - 520) * 256 + t, 128, 128, 128);
  else if (bb < 712) wcv(Wm, Wtm, (bb - 584) * 256 + t, 128, 256, 128);
  else               wcv(Wg2, Wtg2, (bb - 712) * 256 + t, 256, 256, 256);
}

// ---------------- MFMA bf16 GEMM, 2-deep register-prefetch pipeline ----------------
// BM = WR*32 = 64 (A chunks == 256 == one per thread).  Two named register sets,
// K-loop unrolled by 2; loads for tile k+2 issued as soon as their set frees.
// AF32: A fp32 row-stride 300, converted at commit.  MODE 2: GCN2 epilogue.

#define LOADSET(FA, PAW, PB0, PB1, KOFF)                                        \
  if (AF32) {                                                                   \
    const float* xr = Af + (size_t)(bm + arow) * KR + (KOFF) + akc;             \
    if ((KOFF) + akc + 8 <= KR) {                                               \
      float4 q1 = *(const float4*)xr, q2 = *(const float4*)(xr + 4);            \
      FA[0]=q1.x; FA[1]=q1.y; FA[2]=q1.z; FA[3]=q1.w;                           \
      FA[4]=q2.x; FA[5]=q2.y; FA[6]=q2.z; FA[7]=q2.w;                           \
    } else {                                                                    \
      _Pragma("unroll")                                                         \
      for (int j = 0; j < 8; ++j) FA[j] = ((KOFF)+akc+j < KR) ? xr[j] : 0.f;    \
    }                                                                           \
  } else {                                                                      \
    PAW = *(const uint4*)&A[(size_t)(bm + arow) * K + (KOFF) + akc];            \
  }                                                                             \
  if (tid < BCH) PB0 = *(const uint4*)&Bt[(size_t)(bn + arow) * K + (KOFF) + akc]; \
  if (BCH > 256) PB1 = *(const uint4*)&Bt[(size_t)(bn + b1row) * K + (KOFF) + b1kc];

#define COMMITSET(FA, PAW, PB0, PB1)               \
  if (AF32) *(uint4*)&As[arow][akc] = pk8(FA);     \
  else      *(uint4*)&As[arow][akc] = PAW;         \
  if (tid < BCH) *(uint4*)&Bs[arow][akc] = PB0;    \
  if (BCH > 256) *(uint4*)&Bs[b1row][b1kc] = PB1;

#define DO_MFMA()                                                                \
  {                                                                              \
    s8v af[WR], bf[NI];                                                          \
    _Pragma("unroll")                                                            \
    for (int mi = 0; mi < WR; ++mi) af[mi] = *(const s8v*)&As[wm + mi*16 + r][kg]; \
    _Pragma("unroll")                                                            \
    for (int ni = 0; ni < NI; ++ni) bf[ni] = *(const s8v*)&Bs[wn + ni*16 + r][kg]; \
    _Pragma("unroll")                                                            \
    for (int mi = 0; mi < WR; ++mi)                                              \
      _Pragma("unroll")                                                          \
      for (int ni = 0; ni < NI; ++ni)                                            \
        acc[mi][ni] = __builtin_amdgcn_mfma_f32_16x16x32_bf16(af[mi], bf[ni], acc[mi][ni], 0, 0, 0); \
  }

template<int WR, int NI, int MODE, int AF32>
__global__ __launch_bounds__(256) void mgemm_k(const ushort* __restrict__ A,
    const float* __restrict__ Af, const ushort* __restrict__ Bt,
    const ushort* __restrict__ Z, ushort* __restrict__ C, int M, int K, int N) {
  constexpr int BM = WR * 32;      // 64
  constexpr int BN = NI * 32;
  constexpr int KR = 300;
  constexpr int BCH = BN * 4;      // B 16B-chunks (128/256/512)
  __shared__ ushort As[BM][40];
  __shared__ ushort Bs[BN][40];
  int tid = threadIdx.x;
  int wave = tid >> 6, lane = tid & 63;
  int bm = blockIdx.y * BM, bn = blockIdx.x * BN;
  int wm = (wave >> 1) * (WR * 16), wn = (wave & 1) * (NI * 16);
  f4v acc[WR][NI];
#pragma unroll
  for (int a = 0; a < WR; ++a)
#pragma unroll
    for (int b = 0; b < NI; ++b)
#pragma unroll
      for (int q = 0; q < 4; ++q) acc[a][b][q] = 0.f;

  int arow = tid >> 2, akc = (tid & 3) * 8;                  // A / B chunk tid
  int b1row = (256 + tid) >> 2, b1kc = ((256 + tid) & 3) * 8;  // B chunk tid+256

  float fa0[8], fa1[8];
  uint4 paw0, paw1;
  uint4 pb00, pb10, pb01, pb11;

  int r = lane & 15, kg = (lane >> 4) * 8;

  LOADSET(fa0, paw0, pb00, pb10, 0)
  if (32 < K) { LOADSET(fa1, paw1, pb01, pb11, 32) }

  int k0 = 0;
  for (; k0 + 64 <= K; k0 += 64) {
    COMMITSET(fa0, paw0, pb00, pb10)
    __syncthreads();
    if (k0 + 64 < K) { LOADSET(fa0, paw0, pb00, pb10, k0 + 64) }
    DO_MFMA()
    __syncthreads();
    COMMITSET(fa1, paw1, pb01, pb11)
    __syncthreads();
    if (k0 + 96 < K) { LOADSET(fa1, paw1, pb01, pb11, k0 + 96) }
    DO_MFMA()
    __syncthreads();
  }
  if (k0 < K) {   // odd tile count leftover (in set 0)
    COMMITSET(fa0, paw0, pb00, pb10)
    __syncthreads();
    DO_MFMA()
    __syncthreads();
  }

  int col = lane & 15, rowg = (lane >> 4) * 4;
#pragma unroll
  for (int mi = 0; mi < WR; ++mi)
#pragma unroll
    for (int ni = 0; ni < NI; ++ni)
#pragma unroll
      for (int q = 0; q < 4; ++q) {
        int row = bm + wm + mi * 16 + rowg + q;
        int cc = bn + wn + ni * 16 + col;
        size_t idx = (size_t)row * N + cc;
        float v = acc[mi][ni][q];
        if (MODE == 2) v = fmaxf((1.f - C_BETA) * bf2f(Z[idx]) + C_BETA * v, 0.f);
        C[idx] = f2bf(v);
      }
}

// ---------------- graph propagation (packed dst-CSR gather via L2, bf16 I/O) ----------------
// acc = dinv[i]^2*in[i,:] + sum_p w[p]*in[src[p],:]
// WSEL 0: w = pe.y.  WSEL 1: w = dinv[s]*dinv[i] (on-the-fly).
// MODE 0: out = relu(acc + bias).  MODE 1: out = 0.5*acc + 0.5*x0.

template<int D, int MODE, int WSEL>
__global__ __launch_bounds__(256) void prop_k(const ushort* __restrict__ in,
    ushort* __restrict__ out, const int2* __restrict__ pedge,
    const float* __restrict__ dinv, const int* __restrict__ rowptr,
    const float* __restrict__ bias, const ushort* __restrict__ x0) {
  constexpr int TPN = D / 8, NPB = 256 / TPN, BPG = NN / NPB;
  int t = threadIdx.x;
  int bid = swz8(blockIdx.x, BPG);
  int tn = t / TPN, cl = t % TPN;
  int node = bid * NPB + tn;
  int b = node >> 10, i = node & 1023;
  float di = dinv[node];
  float f[8], acc[8];
  uint4 ov = *(const uint4*)&in[(size_t)node * D + cl * 8];
  up8(ov, f);
  float w0 = di * di;
#pragma unroll
  for (int j = 0; j < 8; ++j) acc[j] = w0 * f[j];
  int r0 = rowptr[b * (NN + 1) + i], r1 = rowptr[b * (NN + 1) + i + 1];
  const int2* pe = pedge + (size_t)b * NE;
  const float* dvb = dinv + b * NN;
  const ushort* inb = in + (size_t)b * NN * D;
  int p = r0;
  for (; p + 4 <= r1; p += 4) {      // 4-way unroll: independent loads
    int2 e0 = pe[p], e1 = pe[p + 1], e2 = pe[p + 2], e3 = pe[p + 3];
    float wa, wb2, wc, wd;
    if (WSEL == 0) {
      wa = __int_as_float(e0.y); wb2 = __int_as_float(e1.y);
      wc = __int_as_float(e2.y); wd = __int_as_float(e3.y);
    } else {
      wa = dvb[e0.x] * di; wb2 = dvb[e1.x] * di;
      wc = dvb[e2.x] * di; wd = dvb[e3.x] * di;
    }
    uint4 rv0 = *(const uint4*)&inb[(size_t)e0.x * D + cl * 8];
    uint4 rv1 = *(const uint4*)&inb[(size_t)e1.x * D + cl * 8];
    uint4 rv2 = *(const uint4*)&inb[(size_t)e2.x * D + cl * 8];
    uint4 rv3 = *(const uint4*)&inb[(size_t)e3.x * D + cl * 8];
    up8(rv0, f);
#pragma unroll
    for (int j = 0; j < 8; ++j) acc[j] += wa * f[j];
    up8(rv1, f);
#pragma unroll
    for (int j = 0; j < 8; ++j) acc[j] += wb2 * f[j];
    up8(rv2, f);
#pragma unroll
    for (int j = 0; j < 8; ++j) acc[j] += wc * f[j];
    up8(rv3, f);
#pragma unroll
    for (int j = 0; j < 8; ++j) acc[j] += wd * f[j];
  }
  for (; p < r1; ++p) {
    int2 e = pe[p];
    float w = (WSEL == 0) ? __int_as_float(e.y) : dvb[e.x] * di;
    uint4 rv = *(const uint4*)&inb[(size_t)e.x * D + cl * 8];
    up8(rv, f);
#pragma unroll
    for (int j = 0; j < 8; ++j) acc[j] += w * f[j];
  }
  size_t ob = (size_t)node * D + cl * 8;
  if (MODE == 0) {
#pragma unroll
    for (int j = 0; j < 8; ++j) acc[j] = fmaxf(acc[j] + bias[cl * 8 + j], 0.f);
  } else {
    uint4 xv = *(const uint4*)&x0[ob];
    up8(xv, f);
#pragma unroll
    for (int j = 0; j < 8; ++j) acc[j] = 0.5f * acc[j] + 0.5f * f[j];
  }
  *(uint4*)&out[ob] = pk8(acc);
}

// ---------------- GATv2: fused flash-style with defer-max ----------------
// xlr layout: [node][256]: ch 0-127 = xl, 128-255 = xr.

#define GAT_UPD(P, FL)                                            \
  if (P > m + 8.f) {               /* rare: rescale */            \
    float sc = __expf(m - P);                                     \
    den *= sc;                                                    \
    _Pragma("unroll")                                             \
    for (int j = 0; j < 8; ++j) acc[j] *= sc;                     \
    m = P;                                                        \
    den += 1.f;                                                   \
    _Pragma("unroll")                                             \
    for (int j = 0; j < 8; ++j) acc[j] += FL[j];                  \
  } else {                                                        \
    float ex = __expf(P - m);                                     \
    den += ex;                                                    \
    _Pragma("unroll")                                             \
    for (int j = 0; j < 8; ++j) acc[j] += ex * FL[j];             \
  }

__global__ __launch_bounds__(256) void gat_fused_k(const ushort* __restrict__ xlr,
    const int2* __restrict__ pedge, const int* __restrict__ rowptr,
    const float* __restrict__ att, const float* __restrict__ bg,
    ushort* __restrict__ out) {
  int bid = swz8(blockIdx.x, NN / 16);   // 16 nodes/block
  int t = threadIdx.x;
  int tn = t >> 4, cl = t & 15;
  int node = bid * 16 + tn;
  int b = node >> 10, i = node & 1023;
  int ch = cl * 8;
  int r0 = rowptr[b * (NN + 1) + i], r1 = rowptr[b * (NN + 1) + i + 1];
  const ushort* xb = xlr + (size_t)b * NN * 256;
  const int2* pe = pedge + (size_t)b * NE;
  float fr[8], at[8];
  {
    uint4 rv = *(const uint4*)&xb[(size_t)i * 256 + 128 + ch];  // xr[i] chunk
    up8(rv, fr);
#pragma unroll
    for (int j = 0; j < 8; ++j) at[j] = att[ch + j];
  }
  float m, den, acc[8];
  {
    float fs[8];
    uint4 sv = *(const uint4*)&xb[(size_t)i * 256 + ch];        // xl[i] (self)
    up8(sv, fs);
    float part = 0.f;
#pragma unroll
    for (int j = 0; j < 8; ++j) {
      float v = fs[j] + fr[j];
      part += fmaxf(v, 0.2f * v) * at[j];
    }
    part += __shfl_xor(part, 1);
    part += __shfl_xor(part, 2);
    m = part; den = 1.f;
#pragma unroll
    for (int j = 0; j < 8; ++j) acc[j] = fs[j];
  }
  float fl0[8], fl1[8];
  int p = r0;
  for (; p + 2 <= r1; p += 2) {
    int s0 = pe[p].x, s1 = pe[p + 1].x;
    uint4 v0 = *(const uint4*)&xb[(size_t)s0 * 256 + ch];
    uint4 v1 = *(const uint4*)&xb[(size_t)s1 * 256 + ch];
    up8(v0, fl0); up8(v1, fl1);
    float p0 = 0.f, p1 = 0.f;
#pragma unroll
    for (int j = 0; j < 8; ++j) {
      float a0 = fl0[j] + fr[j];
      float a1 = fl1[j] + fr[j];
      p0 += fmaxf(a0, 0.2f * a0) * at[j];
      p1 += fmaxf(a1, 0.2f * a1) * at[j];
    }
    p0 += __shfl_xor(p0, 1); p0 += __shfl_xor(p0, 2);
    p1 += __shfl_xor(p1, 1); p1 += __shfl_xor(p1, 2);
    GAT_UPD(p0, fl0)
    GAT_UPD(p1, fl1)
  }
  if (p < r1) {
    int s = pe[p].x;
    uint4 v0 = *(const uint4*)&xb[(size_t)s * 256 + ch];
    up8(v0, fl0);
    float p0 = 0.f;
#pragma unroll
    for (int j = 0; j < 8; ++j) {
      float a0 = fl0[j] + fr[j];
      p0 += fmaxf(a0, 0.2f * a0) * at[j];
    }
    p0 += __shfl_xor(p0, 1); p0 += __shfl_xor(p0, 2);
    GAT_UPD(p0, fl0)
  }
  float inv = 1.f / den;
#pragma unroll
  for (int j = 0; j < 8; ++j) acc[j] = fmaxf(acc[j] * inv + bg[ch + j], 0.f);
  *(uint4*)&out[(size_t)node * 128 + ch] = pk8(acc);
}

// ---------------- pooled = column-sum(h7); out = pooled @ Wo + bo ----------------

__global__ __launch_bounds__(256) void pool_part_k(const ushort* __restrict__ h7,
                                                   float* __restrict__ part) {
  int bid = blockIdx.x;                 // NB*8 blocks
  int bgr = bid >> 3, seg = bid & 7;    // 128 rows/segment
  int t = threadIdx.x;
  int rg = t >> 5, cl = t & 31;
  const ushort* hb = h7 + (size_t)bgr * NN * 256;
  float a[8] = {};
  float f[8];
  for (int r = seg * 128 + rg; r < seg * 128 + 128; r += 8) {
    uint4 v = *(const uint4*)&hb[(size_t)r * 256 + cl * 8];
    up8(v, f);
#pragma unroll
    for (int j = 0; j < 8; ++j) a[j] += f[j];
  }
  __shared__ float red[8][256];
#pragma unroll
  for (int j = 0; j < 8; ++j) red[rg][cl * 8 + j] = a[j];
  __syncthreads();
  float s = 0.f;
#pragma unroll
  for (int g = 0; g < 8; ++g) s += red[g][t];
  part[(size_t)bid * 256 + t] = s;
}

__global__ __launch_bounds__(256) void pool_out_k(const float* __restrict__ part,
    const float* __restrict__ Wo, const float* __restrict__ bo, float* __restrict__ out) {
  int bgr = blockIdx.x, t = threadIdx.x;
  float s = 0.f;
#pragma unroll
  for (int g = 0; g < 8; ++g) s += part[(size_t)(bgr * 8 + g) * 256 + t];
  __shared__ float pv[256];
  pv[t] = s;
  __syncthreads();
  if (t < 8) {
    float o = bo[t];
    for (int c = 0; c < 256; ++c) o += pv[c] * Wo[c * 8 + t];
    out[bgr * 8 + t] = o;
  }
}

__global__ void zero_out_k(float* out, int n) {
  int g = blockIdx.x * 256 + threadIdx.x;
  if (g < n) out[g] = 0.f;
}

// ---------------- launch ----------------

extern "C" void kernel_launch(void* const* d_in, const int* in_sizes, int n_in,
                              void* d_out, int out_size, void* d_ws, size_t ws_size,
                              hipStream_t stream) {
  const float* x   = (const float*)d_in[0];
  const int*   ei  = (const int*)d_in[1];
  const float* ew  = (const float*)d_in[2];
  const float* W1  = (const float*)d_in[3];
  const float* b1  = (const float*)d_in[4];
  const float* W2  = (const float*)d_in[5];
  const float* b2  = (const float*)d_in[6];
  const float* W3  = (const float*)d_in[7];
  const float* b3  = (const float*)d_in[8];
  const float* W4  = (const float*)d_in[9];
  const float* b4  = (const float*)d_in[10];
  const float* Wl  = (const float*)d_in[11];
  const float* Wr  = (const float*)d_in[12];
  const float* att = (const float*)d_in[13];
  const float* bg  = (const float*)d_in[14];
  const float* Wg1 = (const float*)d_in[15];
  const float* Wm  = (const float*)d_in[16];
  const float* bm  = (const float*)d_in[17];
  const float* Wg2 = (const float*)d_in[18];
  const float* Wo  = (const float*)d_in[23];
  const float* bo  = (const float*)d_in[24];
  float* out = (float*)d_out;

  const int M = NB * NN;

  char* wp = (char*)d_ws;
  size_t used = 0;
  auto alloc = [&](size_t bytes) -> void* {
    void* p = (void*)wp;
    size_t a = (bytes + 255) & ~(size_t)255;
    wp += a; used += a;
    return p;
  };
  float* dinvw = (float*)alloc((size_t)NB * NN * 4);
  float* dinvu = (float*)alloc((size_t)NB * NN * 4);
  int*   rowptr= (int*)alloc((size_t)NB * (NN + 1) * 4);
  int*   phist = (int*)alloc((size_t)NB * NCH * NN * 4);
  float* pdegw = (float*)alloc((size_t)NB * NCH * NN * 4);
  int2*  peW   = (int2*)alloc((size_t)NB * NE * 8);
  float* part  = (float*)alloc((size_t)NB * 8 * 256 * 4);
  ushort* Wt1  = (ushort*)alloc((size_t)256 * 320 * 2);
  ushort* Wt2  = (ushort*)alloc((size_t)128 * 256 * 2);
  ushort* Wt3  = (ushort*)alloc((size_t)64 * 128 * 2);
  ushort* Wt4  = (ushort*)alloc((size_t)32 * 64 * 2);
  ushort* WtLR = (ushort*)alloc((size_t)256 * 32 * 2);
  ushort* Wtg1 = (ushort*)alloc((size_t)128 * 128 * 2);
  ushort* Wtm  = (ushort*)alloc((size_t)256 * 128 * 2);
  ushort* Wtg2 = (ushort*)alloc((size_t)256 * 256 * 2);
  ushort* B1 = (ushort*)alloc((size_t)M * 256 * 2);   // h1
  ushort* B2 = (ushort*)alloc((size_t)M * 256 * 2);
  ushort* B3 = (ushort*)alloc((size_t)M * 256 * 2);
  ushort* B4 = (ushort*)alloc((size_t)M * 256 * 2);   // xlr
  ushort* B2a = B2, *B2b = B2 + (size_t)M * 128;
  ushort* B3a = B3, *B3b = B3 + (size_t)M * 128;

  if (used > ws_size) {
    zero_out_k<<<(out_size + 255) / 256, 256, 0, stream>>>(out, out_size);
    return;
  }

  // ---- weight conversions ----
  wconv_all_k<<<968, 256, 0, stream>>>(W1, W2, W3, W4, Wl, Wr, Wg1, Wm, Wg2,
                                       Wt1, Wt2, Wt3, Wt4, WtLR, Wtg1, Wtm, Wtg2);

  // ---- CSR build (2-pass counting sort, XCD-affine chunks) ----
  hist_k<<<NB * NCH, 256, 0, stream>>>(ei, ew, phist, pdegw);
  scan2_k<<<NB, 1024, 0, stream>>>(phist, pdegw, dinvw, dinvu, rowptr);
  scatter2_k<<<NB * NCH, 256, 0, stream>>>(ei, ew, phist, dinvw, peW);

  // ---- GCN stack (BM=64 tiles; GEMM1 reads fp32 x directly) ----
  mgemm_k<2,4,0,1><<<dim3(2, M / 64), 256, 0, stream>>>(nullptr, x, Wt1, nullptr, B2, M, 320, 256);
  prop_k<256,0,0><<<M / 8, 256, 0, stream>>>(B2, B1, peW, dinvw, rowptr, b1, nullptr);    // h1
  mgemm_k<2,4,0,0><<<dim3(1, M / 64), 256, 0, stream>>>(B1, nullptr, Wt2, nullptr, B2a, M, 256, 128);
  prop_k<128,0,0><<<M / 16, 256, 0, stream>>>(B2a, B3a, peW, dinvw, rowptr, b2, nullptr); // h2
  mgemm_k<2,2,0,0><<<dim3(1, M / 64), 256, 0, stream>>>(B3a, nullptr, Wt3, nullptr, B2a, M, 128, 64);
  prop_k<64,0,0><<<M / 32, 256, 0, stream>>>(B2a, B3b, peW, dinvw, rowptr, b3, nullptr);  // h3
  mgemm_k<2,1,0,0><<<dim3(1, M / 64), 256, 0, stream>>>(B3b, nullptr, Wt4, nullptr, B2a, M, 64, 32);
  prop_k<32,0,0><<<M / 64, 256, 0, stream>>>(B2a, B2b, peW, dinvw, rowptr, b4, nullptr);  // h4

  // ---- GATv2 (xl|xr one GEMM; fused flash-style attention) ----
  mgemm_k<2,4,0,0><<<dim3(2, M / 64), 256, 0, stream>>>(B2b, nullptr, WtLR, nullptr, B4, M, 32, 256);
  gat_fused_k<<<M / 16, 256, 0, stream>>>(B4, peW, rowptr, att, bg, B2a);                 // hg

  // ---- GCN2Conv #1 (x0 = h2 = B3a) ----
  prop_k<128,1,0><<<M / 16, 256, 0, stream>>>(B2a, B2b, peW, dinvw, rowptr, nullptr, B3a); // z1
  mgemm_k<2,4,2,0><<<dim3(1, M / 64), 256, 0, stream>>>(B2b, nullptr, Wtg1, B2b, B2a, M, 128, 128);

  // ---- GCNConv mid (unweighted norm, on-the-fly du[s]*du[d]) ----
  mgemm_k<2,4,0,0><<<dim3(2, M / 64), 256, 0, stream>>>(B2a, nullptr, Wtm, nullptr, B3, M, 128, 256);
  prop_k<256,0,1><<<M / 8, 256, 0, stream>>>(B3, B2, peW, dinvu, rowptr, bm, nullptr);    // h6

  // ---- GCN2Conv #2 (x0 = h1 = B1) ----
  prop_k<256,1,0><<<M / 8, 256, 0, stream>>>(B2, B3, peW, dinvw, rowptr, nullptr, B1);    // z2
  mgemm_k<2,4,2,0><<<dim3(2, M / 64), 256, 0, stream>>>(B3, nullptr, Wtg2, B3, B2, M, 256, 256);

  // ---- collapsed diff-pool + output projection ----
  pool_part_k<<<NB * 8, 256, 0, stream>>>(B2, part);
  pool_out_k<<<NB, 256, 0, stream>>>(part, Wo, bo, out);
}